// Round 1
// 465.675 us; speedup vs baseline: 1.2385x; 1.2385x over previous
//
#include <hip/hip_runtime.h>

#define N_OCC   20000
#define N_SKILL 50000
#define N_EDGE  600000
#define D_IN    256
#define HID     128
#define OUT_F   64

typedef short bf16x8 __attribute__((ext_vector_type(8)));
typedef float f32x4  __attribute__((ext_vector_type(4)));

__device__ __forceinline__ float bf2f(unsigned short u){
  return __uint_as_float(((unsigned)u) << 16);
}
__device__ __forceinline__ unsigned f2bf_bits(float f){
  unsigned i = __float_as_uint(f);
  return (i + 0x7fffu + ((i >> 16) & 1u)) >> 16;   // RNE
}
__device__ __forceinline__ unsigned f2bf_bits_u(unsigned i){
  return (i + 0x7fffu + ((i >> 16) & 1u)) >> 16;   // RNE from raw f32 bits
}
__device__ __forceinline__ unsigned short f2bf(float f){ return (unsigned short)f2bf_bits(f); }

// ---------- wire-dtype detection ----------
__global__ void k_detect(const unsigned short* __restrict__ x, int* __restrict__ flag){
  int lane = threadIdx.x & 63;
  int cnt = 0;
  for (int i = lane; i < 1024; i += 64){
    unsigned e = ((unsigned)x[i] >> 7) & 0xFFu;
    if (e >= 0xE0u) cnt++;
  }
  #pragma unroll
  for (int s = 1; s < 64; s <<= 1) cnt += __shfl_xor(cnt, s, 64);
  if (lane == 0) *flag = (cnt >= 8) ? 1 : 0;   // 1 => wire is f32
}

// ---------- canonicalize all float tensors to bf16 ----------
#define NT_CONV 18
struct ConvTable {
  const void*     src[NT_CONV];
  unsigned short* dst[NT_CONV];
  int             n[NT_CONV];
  int             blk_off[NT_CONV + 1];   // cumulative blocks (2048 elems/block)
};

__global__ void k_convert(ConvTable t, const int* __restrict__ flag){
  int isf32 = *flag;
  int b = blockIdx.x;
  int ti = 0;
  while (ti < NT_CONV - 1 && b >= t.blk_off[ti + 1]) ti++;
  int lb = b - t.blk_off[ti];
  int i = (lb * 256 + (int)threadIdx.x) * 8;     // element index (8 per thread)
  if (i >= t.n[ti]) return;
  unsigned short* dst = t.dst[ti];
  if (isf32){
    const float* s = (const float*)t.src[ti];
    uint4 lo = *(const uint4*)(s + i);
    uint4 hi = *(const uint4*)(s + i + 4);
    uint4 o;
    o.x = f2bf_bits_u(lo.x) | (f2bf_bits_u(lo.y) << 16);
    o.y = f2bf_bits_u(lo.z) | (f2bf_bits_u(lo.w) << 16);
    o.z = f2bf_bits_u(hi.x) | (f2bf_bits_u(hi.y) << 16);
    o.w = f2bf_bits_u(hi.z) | (f2bf_bits_u(hi.w) << 16);
    *(uint4*)(dst + i) = o;
  } else {
    *(uint4*)(dst + i) = *(const uint4*)((const unsigned short*)t.src[ti] + i);
  }
}

// ---------- transpose all 10 canonical weight matrices W[K][N] -> WT[N][K] ----------
__global__ void k_transpose_all(
    const unsigned short* pWo, unsigned short* tWo,   // 256x128
    const unsigned short* pWs, unsigned short* tWs,   // 256x128
    const unsigned short* w2,  unsigned short* t2,    // 128x128
    const unsigned short* w3,  unsigned short* t3,
    const unsigned short* w4,  unsigned short* t4,
    const unsigned short* w5,  unsigned short* t5,
    const unsigned short* w6,  unsigned short* t6,    // 128x64
    const unsigned short* w7,  unsigned short* t7,
    const unsigned short* w8,  unsigned short* t8,
    const unsigned short* w9,  unsigned short* t9)
{
  int idx = blockIdx.x * blockDim.x + threadIdx.x;
  const unsigned short* in; unsigned short* out; int K, N, base;
  if      (idx <  32768){ in=pWo; out=tWo; K=256; N=128; base=0; }
  else if (idx <  65536){ in=pWs; out=tWs; K=256; N=128; base=32768; }
  else if (idx <  81920){ in=w2;  out=t2;  K=128; N=128; base=65536; }
  else if (idx <  98304){ in=w3;  out=t3;  K=128; N=128; base=81920; }
  else if (idx < 114688){ in=w4;  out=t4;  K=128; N=128; base=98304; }
  else if (idx < 131072){ in=w5;  out=t5;  K=128; N=128; base=114688; }
  else if (idx < 139264){ in=w6;  out=t6;  K=128; N=64;  base=131072; }
  else if (idx < 147456){ in=w7;  out=t7;  K=128; N=64;  base=139264; }
  else if (idx < 155648){ in=w8;  out=t8;  K=128; N=64;  base=147456; }
  else if (idx < 163840){ in=w9;  out=t9;  K=128; N=64;  base=155648; }
  else return;
  int li = idx - base;
  int k = li / N, n = li - k * N;
  out[n * K + k] = in[li];
}

// ---------- degree histogram ----------
__global__ void k_degree(const int* __restrict__ eo, const int* __restrict__ es,
                         int* __restrict__ cnt_s, int* __restrict__ cnt_o)
{
  int i = blockIdx.x * blockDim.x + threadIdx.x;
  if (i < N_EDGE){
    atomicAdd(&cnt_s[es[i]], 1);
    atomicAdd(&cnt_o[eo[i]], 1);
  }
}

// ---------- 3-phase multi-block exclusive scan (both arrays per launch) ----------
#define SCHUNK 2048
#define BS_SKL ((N_SKILL + SCHUNK - 1) / SCHUNK)   // 25
#define BS_OCC ((N_OCC   + SCHUNK - 1) / SCHUNK)   // 10

__global__ void k_scan1(const int* __restrict__ cnt_s, const int* __restrict__ cnt_o,
                        int* __restrict__ bsum)
{
  int b = blockIdx.x;
  const int* in; int n, lb;
  if (b < BS_SKL){ in = cnt_s; n = N_SKILL; lb = b; }
  else           { in = cnt_o; n = N_OCC;   lb = b - BS_SKL; }
  int base = lb * SCHUNK;
  int s = 0;
  for (int i = threadIdx.x; i < SCHUNK; i += 256){
    int idx = base + i;
    if (idx < n) s += in[idx];
  }
  #pragma unroll
  for (int d = 1; d < 64; d <<= 1) s += __shfl_xor(s, d, 64);
  __shared__ int ws[4];
  if ((threadIdx.x & 63) == 0) ws[threadIdx.x >> 6] = s;
  __syncthreads();
  if (threadIdx.x == 0) bsum[b] = ws[0] + ws[1] + ws[2] + ws[3];
}

__global__ void k_scan2(const int* __restrict__ bsum, int* __restrict__ bbase,
                        int* __restrict__ off_s, int* __restrict__ off_o)
{
  int lane = threadIdx.x;   // 64 threads = 1 wave
  int v = (lane < BS_SKL) ? bsum[lane] : 0;
  int x = v;
  #pragma unroll
  for (int d = 1; d < 64; d <<= 1){ int t = __shfl_up(x, d, 64); if (lane >= d) x += t; }
  if (lane < BS_SKL) bbase[lane] = x - v;
  int v2 = (lane < BS_OCC) ? bsum[BS_SKL + lane] : 0;
  int x2 = v2;
  #pragma unroll
  for (int d = 1; d < 64; d <<= 1){ int t = __shfl_up(x2, d, 64); if (lane >= d) x2 += t; }
  if (lane < BS_OCC) bbase[BS_SKL + lane] = x2 - v2;
  if (lane == 0){ off_s[N_SKILL] = N_EDGE; off_o[N_OCC] = N_EDGE; }
}

__global__ void k_scan3(const int* __restrict__ cnt_s, const int* __restrict__ cnt_o,
                        const int* __restrict__ bbase,
                        int* __restrict__ off_s, int* __restrict__ off_o)
{
  int b = blockIdx.x;
  const int* in; int* out; int n, lb;
  if (b < BS_SKL){ in = cnt_s; out = off_s; n = N_SKILL; lb = b; }
  else           { in = cnt_o; out = off_o; n = N_OCC;   lb = b - BS_SKL; }
  int base = lb * SCHUNK;
  int i0 = base + (int)threadIdx.x * 8;
  int v[8]; int t = 0;
  #pragma unroll
  for (int j = 0; j < 8; ++j){ int idx = i0 + j; v[j] = (idx < n) ? in[idx] : 0; t += v[j]; }
  int lane = threadIdx.x & 63, wv = threadIdx.x >> 6;
  int x = t;
  #pragma unroll
  for (int d = 1; d < 64; d <<= 1){ int u = __shfl_up(x, d, 64); if (lane >= d) x += u; }
  __shared__ int ws[4];
  if (lane == 63) ws[wv] = x;
  __syncthreads();
  int woff = 0;
  for (int w = 0; w < wv; ++w) woff += ws[w];
  int excl = bbase[b] + woff + (x - t);
  #pragma unroll
  for (int j = 0; j < 8; ++j){ int idx = i0 + j; if (idx < n) out[idx] = excl; excl += v[j]; }
}

// ---------- CSR build via two-pass bucket counting sort ----------
// Pass 1: LDS-bin edges by dst-range bucket, reserve contiguous global space with
// one atomic per (block,bucket), flush coalesced (src,dst) pairs.
// Pass 2: one block per bucket scatters src into the bucket's contiguous CSR
// window (L2-resident) using LDS per-dst counters.
#define EPB      4096
#define BIN_BLKS ((N_EDGE + EPB - 1) / EPB)         // 147
#define SH_S 9
#define SH_O 8
#define NB_S ((N_SKILL + (1 << SH_S) - 1) >> SH_S)  // 98
#define NB_O ((N_OCC   + (1 << SH_O) - 1) >> SH_O)  // 79

__launch_bounds__(256)
__global__ void k_bin(const int* __restrict__ eo, const int* __restrict__ es,
                      const int* __restrict__ off_s, const int* __restrict__ off_o,
                      int* __restrict__ bcur_s, int* __restrict__ bcur_o,
                      uint2* __restrict__ pair_s, uint2* __restrict__ pair_o)
{
  int b = blockIdx.x;
  int side = (b >= BIN_BLKS) ? 1 : 0;
  int lb = side ? b - BIN_BLKS : b;
  const int* dste = side ? eo : es;
  const int* srce = side ? es : eo;
  const int* off  = side ? off_o : off_s;
  int* bcur       = side ? bcur_o : bcur_s;
  uint2* pairs    = side ? pair_o : pair_s;
  const int NB = side ? NB_O : NB_S;
  const int SH = side ? SH_O : SH_S;

  __shared__ int cntL[NB_S], gbaseL[NB_S], lbaseL[NB_S], runL[NB_S];
  __shared__ int sc[128];
  __shared__ uint2 stage[EPB];   // 32 KB
  __shared__ int gpos[EPB];      // 16 KB

  int e0 = lb * EPB;
  int e1 = min(e0 + EPB, N_EDGE);

  for (int i = threadIdx.x; i < NB; i += 256){ cntL[i] = 0; runL[i] = 0; }
  __syncthreads();
  for (int e = e0 + threadIdx.x; e < e1; e += 256)
    atomicAdd(&cntL[dste[e] >> SH], 1);
  __syncthreads();
  // inclusive Hillis-Steele scan of bucket counts (padded to 128)
  if (threadIdx.x < 128) sc[threadIdx.x] = (threadIdx.x < NB) ? cntL[threadIdx.x] : 0;
  __syncthreads();
  for (int d = 1; d < 128; d <<= 1){
    int v = 0;
    if (threadIdx.x < 128 && threadIdx.x >= d) v = sc[threadIdx.x - d];
    __syncthreads();
    if (threadIdx.x < 128) sc[threadIdx.x] += v;
    __syncthreads();
  }
  if (threadIdx.x < NB){
    int c = cntL[threadIdx.x];
    lbaseL[threadIdx.x] = sc[threadIdx.x] - c;
    gbaseL[threadIdx.x] = off[threadIdx.x << SH] + atomicAdd(&bcur[threadIdx.x], c);
  }
  __syncthreads();
  for (int e = e0 + threadIdx.x; e < e1; e += 256){
    int d = dste[e], s = srce[e];
    int bk = d >> SH;
    int r = atomicAdd(&runL[bk], 1);
    int lp = lbaseL[bk] + r;
    stage[lp] = make_uint2((unsigned)s, (unsigned)d);
    gpos[lp] = gbaseL[bk] + r;
  }
  __syncthreads();
  int tot = e1 - e0;
  for (int i = threadIdx.x; i < tot; i += 256)
    pairs[gpos[i]] = stage[i];     // consecutive within each bucket run -> coalesced
}

__launch_bounds__(256)
__global__ void k_fill2(const uint2* __restrict__ pair_s, const uint2* __restrict__ pair_o,
                        const int* __restrict__ off_s, const int* __restrict__ off_o,
                        int* __restrict__ csr_s, int* __restrict__ csr_o)
{
  int b = blockIdx.x;
  int side = (b >= NB_S) ? 1 : 0;
  int lb = side ? b - NB_S : b;
  const uint2* pairs = side ? pair_o : pair_s;
  const int* off = side ? off_o : off_s;
  int* csr = side ? csr_o : csr_s;
  int SH = side ? SH_O : SH_S;
  int nd_tot = side ? N_OCC : N_SKILL;
  int d0 = lb << SH;
  int d1 = min(d0 + (1 << SH), nd_tot);
  int nd = d1 - d0;
  __shared__ int cur[1 << SH_S];
  __shared__ int offL[(1 << SH_S) + 1];
  for (int i = threadIdx.x; i < nd; i += 256) cur[i] = 0;
  for (int i = threadIdx.x; i <= nd; i += 256) offL[i] = off[d0 + i];
  __syncthreads();
  int p0 = offL[0], p1 = offL[nd];
  for (int i = p0 + (int)threadIdx.x; i < p1; i += 256){
    uint2 pr = pairs[i];
    int d = (int)pr.y - d0;
    int p = offL[d] + atomicAdd(&cur[d], 1);
    csr[p] = (int)pr.x;    // scattered, but within one contiguous L2-resident window
  }
}

// ---------- segment mean: one wave per dst node, 128 bf16 feats ----------
__launch_bounds__(256)
__global__ void k_seg_mean(const unsigned short* __restrict__ feat,
                           const int* __restrict__ off, const int* __restrict__ csr,
                           unsigned short* __restrict__ out, int n_dst)
{
  int gw = (int)((blockIdx.x * blockDim.x + threadIdx.x) >> 6);
  if (gw >= n_dst) return;
  int lane = threadIdx.x & 63;
  int r = lane >> 4;
  int c = lane & 15;
  int beg = off[gw], end = off[gw + 1];
  float acc[8];
  #pragma unroll
  for (int j = 0; j < 8; ++j) acc[j] = 0.0f;
  for (int e = beg + r; e < end; e += 4){
    int s = csr[e];
    uint4 v = *(const uint4*)(feat + ((size_t)s << 7) + (c << 3));
    acc[0] += __uint_as_float(v.x << 16); acc[1] += __uint_as_float(v.x & 0xffff0000u);
    acc[2] += __uint_as_float(v.y << 16); acc[3] += __uint_as_float(v.y & 0xffff0000u);
    acc[4] += __uint_as_float(v.z << 16); acc[5] += __uint_as_float(v.z & 0xffff0000u);
    acc[6] += __uint_as_float(v.w << 16); acc[7] += __uint_as_float(v.w & 0xffff0000u);
  }
  #pragma unroll
  for (int j = 0; j < 8; ++j){
    acc[j] += __shfl_xor(acc[j], 16, 64);
    acc[j] += __shfl_xor(acc[j], 32, 64);
  }
  if (r == 0){
    int cnt = end - beg;
    float inv = 1.0f / (float)(cnt > 0 ? cnt : 1);
    uint4 o;
    o.x = f2bf_bits(acc[0] * inv) | (f2bf_bits(acc[1] * inv) << 16);
    o.y = f2bf_bits(acc[2] * inv) | (f2bf_bits(acc[3] * inv) << 16);
    o.z = f2bf_bits(acc[4] * inv) | (f2bf_bits(acc[5] * inv) << 16);
    o.w = f2bf_bits(acc[6] * inv) | (f2bf_bits(acc[7] * inv) << 16);
    *(uint4*)(out + ((size_t)gw << 7) + (c << 3)) = o;
  }
}

// ---------- fused GEMM: C = act(A1@W1 + [A2@W2] + bias) ----------
template<int NCOLS>
__launch_bounds__(256)
__global__ void k_gemm(const unsigned short* __restrict__ A1,
                       const unsigned short* __restrict__ W1T, int K1,
                       const unsigned short* __restrict__ A2,
                       const unsigned short* __restrict__ W2T, int K2,
                       const unsigned short* __restrict__ bias,
                       void* __restrict__ C, size_t c_off,
                       int M, int do_relu,
                       int to_wire, const int* __restrict__ wire_flag)
{
  constexpr int NT = NCOLS / 16;
  constexpr int MW = 2;
  const int lane = threadIdx.x & 63;
  const int wv   = threadIdx.x >> 6;
  const int q    = lane >> 4;
  const int mr   = lane & 15;
  const int m0   = blockIdx.x * (4 * MW * 16) + wv * (MW * 16);
  const int koff = q * 8;

  f32x4 acc[MW][NT];
  #pragma unroll
  for (int mw = 0; mw < MW; ++mw)
    #pragma unroll
    for (int nt = 0; nt < NT; ++nt)
      #pragma unroll
      for (int j = 0; j < 4; ++j) acc[mw][nt][j] = 0.0f;

  for (int k0 = 0; k0 < K1; k0 += 32){
    bf16x8 a[MW], b[NT];
    #pragma unroll
    for (int mw = 0; mw < MW; ++mw){
      int row = m0 + mw * 16 + mr;
      if (row < M){
        a[mw] = *(const bf16x8*)(A1 + (size_t)row * K1 + k0 + koff);
      } else {
        #pragma unroll
        for (int j = 0; j < 8; ++j) a[mw][j] = 0;
      }
    }
    #pragma unroll
    for (int nt = 0; nt < NT; ++nt)
      b[nt] = *(const bf16x8*)(W1T + (size_t)(nt * 16 + mr) * K1 + k0 + koff);
    #pragma unroll
    for (int mw = 0; mw < MW; ++mw)
      #pragma unroll
      for (int nt = 0; nt < NT; ++nt)
        acc[mw][nt] = __builtin_amdgcn_mfma_f32_16x16x32_bf16(a[mw], b[nt], acc[mw][nt], 0, 0, 0);
  }

  if (A2 != nullptr){
    for (int k0 = 0; k0 < K2; k0 += 32){
      bf16x8 a[MW], b[NT];
      #pragma unroll
      for (int mw = 0; mw < MW; ++mw){
        int row = m0 + mw * 16 + mr;
        if (row < M){
          a[mw] = *(const bf16x8*)(A2 + (size_t)row * K2 + k0 + koff);
        } else {
          #pragma unroll
          for (int j = 0; j < 8; ++j) a[mw][j] = 0;
        }
      }
      #pragma unroll
      for (int nt = 0; nt < NT; ++nt)
        b[nt] = *(const bf16x8*)(W2T + (size_t)(nt * 16 + mr) * K2 + k0 + koff);
      #pragma unroll
      for (int mw = 0; mw < MW; ++mw)
        #pragma unroll
        for (int nt = 0; nt < NT; ++nt)
          acc[mw][nt] = __builtin_amdgcn_mfma_f32_16x16x32_bf16(a[mw], b[nt], acc[mw][nt], 0, 0, 0);
    }
  }

  const int wf = to_wire ? *wire_flag : 0;   // 1 => write f32
  #pragma unroll
  for (int mw = 0; mw < MW; ++mw){
    #pragma unroll
    for (int nt = 0; nt < NT; ++nt){
      int col = nt * 16 + mr;
      float bv = bf2f(bias[col]);
      #pragma unroll
      for (int r4 = 0; r4 < 4; ++r4){
        int row = m0 + mw * 16 + q * 4 + r4;
        if (row < M){
          float v = acc[mw][nt][r4] + bv;
          if (do_relu) v = fmaxf(v, 0.0f);
          size_t idx = c_off + (size_t)row * NCOLS + col;
          if (wf) ((float*)C)[idx] = v;
          else    ((unsigned short*)C)[idx] = f2bf(v);
        }
      }
    }
  }
}

extern "C" void kernel_launch(void* const* d_in, const int* in_sizes, int n_in,
                              void* d_out, int out_size, void* d_ws, size_t ws_size,
                              hipStream_t stream)
{
  const void* raw[20];
  for (int i = 0; i < 20; ++i) raw[i] = d_in[i];
  const int* edge_occ   = (const int*)d_in[2];
  const int* edge_skill = (const int*)d_in[3];

  char* ws = (char*)d_ws;
  size_t off = 0;
  auto alloc = [&](size_t bytes) -> char* {
    char* p = ws + off;
    off = (off + bytes + 255) & ~(size_t)255;
    return p;
  };

  int* wire_flag = (int*)alloc(4);

  // canonical bf16 copies of all float tensors (18 of them)
  static const int cn[NT_CONV] = {
    N_OCC * D_IN, N_SKILL * D_IN,                // x_occ, x_skill
    D_IN * HID, HID, D_IN * HID, HID,            // pW_occ, pb_occ, pW_skill, pb_skill
    HID * HID, HID, HID * HID,                   // c1_os_Wl, bl, Wr
    HID * HID, HID, HID * HID,                   // c1_so_Wl, bl, Wr
    HID * OUT_F, OUT_F, HID * OUT_F,             // c2_os_Wl, bl, Wr
    HID * OUT_F, OUT_F, HID * OUT_F              // c2_so_Wl, bl, Wr
  };
  static const int raw_idx[NT_CONV] = {0,1, 4,5,6,7, 8,9,10, 11,12,13, 14,15,16, 17,18,19};
  unsigned short* can[NT_CONV];
  for (int i = 0; i < NT_CONV; ++i) can[i] = (unsigned short*)alloc((size_t)cn[i] * 2);

  ConvTable ct;
  ct.blk_off[0] = 0;
  for (int i = 0; i < NT_CONV; ++i){
    ct.src[i] = raw[raw_idx[i]];
    ct.dst[i] = can[i];
    ct.n[i]   = cn[i];
    ct.blk_off[i + 1] = ct.blk_off[i] + (cn[i] + 2047) / 2048;
  }
  const int conv_blocks = ct.blk_off[NT_CONV];

  const unsigned short* c_xocc   = can[0];
  const unsigned short* c_xskill = can[1];
  const unsigned short* c_pWo = can[2],  *c_pbo = can[3];
  const unsigned short* c_pWs = can[4],  *c_pbs = can[5];
  const unsigned short* c1osWl = can[6], *c1osbl = can[7], *c1osWr = can[8];
  const unsigned short* c1soWl = can[9], *c1sobl = can[10], *c1soWr = can[11];
  const unsigned short* c2osWl = can[12], *c2osbl = can[13], *c2osWr = can[14];
  const unsigned short* c2soWl = can[15], *c2sobl = can[16], *c2soWr = can[17];

  // transposed weights
  unsigned short* wt_pocc   = (unsigned short*)alloc(32768 * 2);
  unsigned short* wt_pskill = (unsigned short*)alloc(32768 * 2);
  unsigned short* wt_c1osWl = (unsigned short*)alloc(16384 * 2);
  unsigned short* wt_c1osWr = (unsigned short*)alloc(16384 * 2);
  unsigned short* wt_c1soWl = (unsigned short*)alloc(16384 * 2);
  unsigned short* wt_c1soWr = (unsigned short*)alloc(16384 * 2);
  unsigned short* wt_c2osWl = (unsigned short*)alloc(8192 * 2);
  unsigned short* wt_c2osWr = (unsigned short*)alloc(8192 * 2);
  unsigned short* wt_c2soWl = (unsigned short*)alloc(8192 * 2);
  unsigned short* wt_c2soWr = (unsigned short*)alloc(8192 * 2);

  // zero-initialized region: degree counters + bucket cursors
  char* zero_base = alloc((size_t)(N_SKILL + N_OCC + NB_S + NB_O) * 4);
  int* cnt_s  = (int*)zero_base;
  int* cnt_o  = cnt_s + N_SKILL;
  int* bcur_s = cnt_o + N_OCC;
  int* bcur_o = bcur_s + NB_S;
  size_t zero_bytes = (size_t)(N_SKILL + N_OCC + NB_S + NB_O) * 4;

  int* off_s = (int*)alloc((N_SKILL + 1) * 4);
  int* off_o = (int*)alloc((N_OCC + 1) * 4);
  int* csr_s = (int*)alloc((size_t)N_EDGE * 4);
  int* csr_o = (int*)alloc((size_t)N_EDGE * 4);
  int* bsum  = (int*)alloc((BS_SKL + BS_OCC) * 4);
  int* bbase = (int*)alloc((BS_SKL + BS_OCC) * 4);
  uint2* pair_s = (uint2*)alloc((size_t)N_EDGE * 8);
  uint2* pair_o = (uint2*)alloc((size_t)N_EDGE * 8);

  unsigned short* h_occ   = (unsigned short*)alloc((size_t)N_OCC * HID * 2);
  unsigned short* h_skill = (unsigned short*)alloc((size_t)N_SKILL * HID * 2);
  unsigned short* mean_s  = (unsigned short*)alloc((size_t)N_SKILL * HID * 2);
  unsigned short* mean_o  = (unsigned short*)alloc((size_t)N_OCC * HID * 2);
  unsigned short* s1      = (unsigned short*)alloc((size_t)N_SKILL * HID * 2);
  unsigned short* o1      = (unsigned short*)alloc((size_t)N_OCC * HID * 2);

  const int EB = (N_EDGE + 255) / 256;
  const int G_OCC  = (N_OCC + 127) / 128;
  const int G_SKL  = (N_SKILL + 127) / 128;
  const int SM_SKL = (N_SKILL + 3) / 4;
  const int SM_OCC = (N_OCC + 3) / 4;

  hipMemsetAsync(zero_base, 0, zero_bytes, stream);

  k_detect<<<1, 64, 0, stream>>>((const unsigned short*)raw[0], wire_flag);
  k_convert<<<conv_blocks, 256, 0, stream>>>(ct, wire_flag);

  k_transpose_all<<<640, 256, 0, stream>>>(
      c_pWo, wt_pocc, c_pWs, wt_pskill,
      c1osWl, wt_c1osWl, c1osWr, wt_c1osWr,
      c1soWl, wt_c1soWl, c1soWr, wt_c1soWr,
      c2osWl, wt_c2osWl, c2osWr, wt_c2osWr,
      c2soWl, wt_c2soWl, c2soWr, wt_c2soWr);

  // CSR build: degree -> 3-phase scan -> bucket-bin -> in-bucket scatter
  k_degree<<<EB, 256, 0, stream>>>(edge_occ, edge_skill, cnt_s, cnt_o);
  k_scan1<<<BS_SKL + BS_OCC, 256, 0, stream>>>(cnt_s, cnt_o, bsum);
  k_scan2<<<1, 64, 0, stream>>>(bsum, bbase, off_s, off_o);
  k_scan3<<<BS_SKL + BS_OCC, 256, 0, stream>>>(cnt_s, cnt_o, bbase, off_s, off_o);
  k_bin<<<2 * BIN_BLKS, 256, 0, stream>>>(edge_occ, edge_skill, off_s, off_o,
                                          bcur_s, bcur_o, pair_s, pair_o);
  k_fill2<<<NB_S + NB_O, 256, 0, stream>>>(pair_s, pair_o, off_s, off_o, csr_s, csr_o);

  // input projections + relu
  k_gemm<128><<<G_OCC, 256, 0, stream>>>(c_xocc, wt_pocc, D_IN, nullptr, nullptr, 0,
                                         c_pbo, h_occ, 0, N_OCC, 1, 0, wire_flag);
  k_gemm<128><<<G_SKL, 256, 0, stream>>>(c_xskill, wt_pskill, D_IN, nullptr, nullptr, 0,
                                         c_pbs, h_skill, 0, N_SKILL, 1, 0, wire_flag);

  // conv1 aggregation
  k_seg_mean<<<SM_SKL, 256, 0, stream>>>(h_occ, off_s, csr_s, mean_s, N_SKILL);
  k_seg_mean<<<SM_OCC, 256, 0, stream>>>(h_skill, off_o, csr_o, mean_o, N_OCC);

  // conv1 linear
  k_gemm<128><<<G_SKL, 256, 0, stream>>>(mean_s, wt_c1osWl, HID, h_skill, wt_c1osWr, HID,
                                         c1osbl, s1, 0, N_SKILL, 1, 0, wire_flag);
  k_gemm<128><<<G_OCC, 256, 0, stream>>>(mean_o, wt_c1soWl, HID, h_occ, wt_c1soWr, HID,
                                         c1sobl, o1, 0, N_OCC, 1, 0, wire_flag);

  // conv2 aggregation
  k_seg_mean<<<SM_SKL, 256, 0, stream>>>(o1, off_s, csr_s, mean_s, N_SKILL);
  k_seg_mean<<<SM_OCC, 256, 0, stream>>>(s1, off_o, csr_o, mean_o, N_OCC);

  // conv2 linear -> d_out (o2 at element offset 0, s2 after it)
  k_gemm<64><<<G_SKL, 256, 0, stream>>>(mean_s, wt_c2osWl, HID, s1, wt_c2osWr, HID,
                                        c2osbl, d_out, (size_t)N_OCC * OUT_F, N_SKILL, 0, 1, wire_flag);
  k_gemm<64><<<G_OCC, 256, 0, stream>>>(mean_o, wt_c2soWl, HID, o1, wt_c2soWr, HID,
                                        c2sobl, d_out, 0, N_OCC, 0, 1, wire_flag);
}

// Round 2
// 412.766 us; speedup vs baseline: 1.3972x; 1.1282x over previous
//
#include <hip/hip_runtime.h>

#define N_OCC   20000
#define N_SKILL 50000
#define N_EDGE  600000
#define D_IN    256
#define HID     128
#define OUT_F   64

typedef short bf16x8 __attribute__((ext_vector_type(8)));
typedef float f32x4  __attribute__((ext_vector_type(4)));

__device__ __forceinline__ float bf2f(unsigned short u){
  return __uint_as_float(((unsigned)u) << 16);
}
__device__ __forceinline__ unsigned f2bf_bits(float f){
  unsigned i = __float_as_uint(f);
  return (i + 0x7fffu + ((i >> 16) & 1u)) >> 16;   // RNE
}
__device__ __forceinline__ unsigned f2bf_bits_u(unsigned i){
  return (i + 0x7fffu + ((i >> 16) & 1u)) >> 16;   // RNE from raw f32 bits
}
__device__ __forceinline__ unsigned short f2bf(float f){ return (unsigned short)f2bf_bits(f); }

// ---------- wire-dtype detection ----------
__global__ void k_detect(const unsigned short* __restrict__ x, int* __restrict__ flag){
  int lane = threadIdx.x & 63;
  int cnt = 0;
  for (int i = lane; i < 1024; i += 64){
    unsigned e = ((unsigned)x[i] >> 7) & 0xFFu;
    if (e >= 0xE0u) cnt++;
  }
  #pragma unroll
  for (int s = 1; s < 64; s <<= 1) cnt += __shfl_xor(cnt, s, 64);
  if (lane == 0) *flag = (cnt >= 8) ? 1 : 0;   // 1 => wire is f32
}

// ---------- canonicalize all float tensors to bf16 ----------
#define NT_CONV 18
struct ConvTable {
  const void*     src[NT_CONV];
  unsigned short* dst[NT_CONV];
  int             n[NT_CONV];
  int             blk_off[NT_CONV + 1];   // cumulative blocks (2048 elems/block)
};

__global__ void k_convert(ConvTable t, const int* __restrict__ flag){
  int isf32 = *flag;
  int b = blockIdx.x;
  int ti = 0;
  while (ti < NT_CONV - 1 && b >= t.blk_off[ti + 1]) ti++;
  int lb = b - t.blk_off[ti];
  int i = (lb * 256 + (int)threadIdx.x) * 8;     // element index (8 per thread)
  if (i >= t.n[ti]) return;
  unsigned short* dst = t.dst[ti];
  if (isf32){
    const float* s = (const float*)t.src[ti];
    uint4 lo = *(const uint4*)(s + i);
    uint4 hi = *(const uint4*)(s + i + 4);
    uint4 o;
    o.x = f2bf_bits_u(lo.x) | (f2bf_bits_u(lo.y) << 16);
    o.y = f2bf_bits_u(lo.z) | (f2bf_bits_u(lo.w) << 16);
    o.z = f2bf_bits_u(hi.x) | (f2bf_bits_u(hi.y) << 16);
    o.w = f2bf_bits_u(hi.z) | (f2bf_bits_u(hi.w) << 16);
    *(uint4*)(dst + i) = o;
  } else {
    *(uint4*)(dst + i) = *(const uint4*)((const unsigned short*)t.src[ti] + i);
  }
}

// ---------- transpose all 10 canonical weight matrices W[K][N] -> WT[N][K] ----------
__global__ void k_transpose_all(
    const unsigned short* pWo, unsigned short* tWo,   // 256x128
    const unsigned short* pWs, unsigned short* tWs,   // 256x128
    const unsigned short* w2,  unsigned short* t2,    // 128x128
    const unsigned short* w3,  unsigned short* t3,
    const unsigned short* w4,  unsigned short* t4,
    const unsigned short* w5,  unsigned short* t5,
    const unsigned short* w6,  unsigned short* t6,    // 128x64
    const unsigned short* w7,  unsigned short* t7,
    const unsigned short* w8,  unsigned short* t8,
    const unsigned short* w9,  unsigned short* t9)
{
  int idx = blockIdx.x * blockDim.x + threadIdx.x;
  const unsigned short* in; unsigned short* out; int K, N, base;
  if      (idx <  32768){ in=pWo; out=tWo; K=256; N=128; base=0; }
  else if (idx <  65536){ in=pWs; out=tWs; K=256; N=128; base=32768; }
  else if (idx <  81920){ in=w2;  out=t2;  K=128; N=128; base=65536; }
  else if (idx <  98304){ in=w3;  out=t3;  K=128; N=128; base=81920; }
  else if (idx < 114688){ in=w4;  out=t4;  K=128; N=128; base=98304; }
  else if (idx < 131072){ in=w5;  out=t5;  K=128; N=128; base=114688; }
  else if (idx < 139264){ in=w6;  out=t6;  K=128; N=64;  base=131072; }
  else if (idx < 147456){ in=w7;  out=t7;  K=128; N=64;  base=139264; }
  else if (idx < 155648){ in=w8;  out=t8;  K=128; N=64;  base=147456; }
  else if (idx < 163840){ in=w9;  out=t9;  K=128; N=64;  base=155648; }
  else return;
  int li = idx - base;
  int k = li / N, n = li - k * N;
  out[n * K + k] = in[li];
}

// ---------- CSR build: bucket counting sort, no node-level global atomics ----------
// A: k_bincount — LDS bucket histogram, 1 global atomic per (block,bucket)
// B: k_bscan    — scan 98+79 bucket totals -> bucket base offsets
// C: k_bin      — stage (src,dst) pairs bucket-contiguously (coalesced flush)
// D: k_build    — per bucket: LDS node histogram + scan -> write off[] segment,
//                 scatter src into the bucket's contiguous L2-resident csr window
#define EPB      4096
#define BIN_BLKS ((N_EDGE + EPB - 1) / EPB)         // 147
#define SH_S 9
#define SH_O 8
#define NB_S ((N_SKILL + (1 << SH_S) - 1) >> SH_S)  // 98
#define NB_O ((N_OCC   + (1 << SH_O) - 1) >> SH_O)  // 79

__launch_bounds__(256)
__global__ void k_bincount(const int* __restrict__ eo, const int* __restrict__ es,
                           int* __restrict__ bkcnt_s, int* __restrict__ bkcnt_o)
{
  int b = blockIdx.x;
  int side = (b >= BIN_BLKS) ? 1 : 0;
  int lb = side ? b - BIN_BLKS : b;
  const int* dste = side ? eo : es;
  int* bkcnt = side ? bkcnt_o : bkcnt_s;
  const int NB = side ? NB_O : NB_S;
  const int SH = side ? SH_O : SH_S;
  __shared__ int cntL[NB_S];
  for (int i = threadIdx.x; i < NB; i += 256) cntL[i] = 0;
  __syncthreads();
  int e0 = lb * EPB, e1 = min(e0 + EPB, N_EDGE);
  for (int e = e0 + threadIdx.x; e < e1; e += 256)
    atomicAdd(&cntL[dste[e] >> SH], 1);
  __syncthreads();
  for (int i = threadIdx.x; i < NB; i += 256)
    if (cntL[i]) atomicAdd(&bkcnt[i], cntL[i]);
}

__global__ void k_bscan(const int* __restrict__ bkcnt_s, const int* __restrict__ bkcnt_o,
                        int* __restrict__ boff_s, int* __restrict__ boff_o,
                        int* __restrict__ off_s, int* __restrict__ off_o)
{
  __shared__ int sc[128];
  int t = threadIdx.x;   // 128 threads
  // skill-side buckets
  int v = (t < NB_S) ? bkcnt_s[t] : 0;
  sc[t] = v;
  __syncthreads();
  for (int d = 1; d < 128; d <<= 1){
    int u = (t >= d) ? sc[t - d] : 0;
    __syncthreads();
    sc[t] += u;
    __syncthreads();
  }
  if (t < NB_S) boff_s[t] = sc[t] - v;
  if (t == 0){ boff_s[NB_S] = N_EDGE; off_s[N_SKILL] = N_EDGE; }
  __syncthreads();
  // occ-side buckets
  int v2 = (t < NB_O) ? bkcnt_o[t] : 0;
  sc[t] = v2;
  __syncthreads();
  for (int d = 1; d < 128; d <<= 1){
    int u = (t >= d) ? sc[t - d] : 0;
    __syncthreads();
    sc[t] += u;
    __syncthreads();
  }
  if (t < NB_O) boff_o[t] = sc[t] - v2;
  if (t == 0){ boff_o[NB_O] = N_EDGE; off_o[N_OCC] = N_EDGE; }
}

__launch_bounds__(256)
__global__ void k_bin(const int* __restrict__ eo, const int* __restrict__ es,
                      const int* __restrict__ boff_s, const int* __restrict__ boff_o,
                      int* __restrict__ bcur_s, int* __restrict__ bcur_o,
                      uint2* __restrict__ pair_s, uint2* __restrict__ pair_o)
{
  int b = blockIdx.x;
  int side = (b >= BIN_BLKS) ? 1 : 0;
  int lb = side ? b - BIN_BLKS : b;
  const int* dste = side ? eo : es;
  const int* srce = side ? es : eo;
  const int* boff = side ? boff_o : boff_s;
  int* bcur       = side ? bcur_o : bcur_s;
  uint2* pairs    = side ? pair_o : pair_s;
  const int NB = side ? NB_O : NB_S;
  const int SH = side ? SH_O : SH_S;

  __shared__ int cntL[NB_S], gbaseL[NB_S], lbaseL[NB_S], runL[NB_S];
  __shared__ int sc[128];
  __shared__ uint2 stage[EPB];   // 32 KB
  __shared__ int gpos[EPB];      // 16 KB

  int e0 = lb * EPB;
  int e1 = min(e0 + EPB, N_EDGE);

  for (int i = threadIdx.x; i < NB; i += 256){ cntL[i] = 0; runL[i] = 0; }
  __syncthreads();
  for (int e = e0 + threadIdx.x; e < e1; e += 256)
    atomicAdd(&cntL[dste[e] >> SH], 1);
  __syncthreads();
  // inclusive Hillis-Steele scan of bucket counts (padded to 128)
  if (threadIdx.x < 128) sc[threadIdx.x] = (threadIdx.x < NB) ? cntL[threadIdx.x] : 0;
  __syncthreads();
  for (int d = 1; d < 128; d <<= 1){
    int v = 0;
    if (threadIdx.x < 128 && threadIdx.x >= d) v = sc[threadIdx.x - d];
    __syncthreads();
    if (threadIdx.x < 128) sc[threadIdx.x] += v;
    __syncthreads();
  }
  if (threadIdx.x < NB){
    int c = cntL[threadIdx.x];
    lbaseL[threadIdx.x] = sc[threadIdx.x] - c;
    gbaseL[threadIdx.x] = boff[threadIdx.x] + atomicAdd(&bcur[threadIdx.x], c);
  }
  __syncthreads();
  for (int e = e0 + threadIdx.x; e < e1; e += 256){
    int d = dste[e], s = srce[e];
    int bk = d >> SH;
    int r = atomicAdd(&runL[bk], 1);
    int lp = lbaseL[bk] + r;
    stage[lp] = make_uint2((unsigned)s, (unsigned)d);
    gpos[lp] = gbaseL[bk] + r;
  }
  __syncthreads();
  int tot = e1 - e0;
  for (int i = threadIdx.x; i < tot; i += 256)
    pairs[gpos[i]] = stage[i];     // consecutive within each bucket run -> coalesced
}

__launch_bounds__(256)
__global__ void k_build(const uint2* __restrict__ pair_s, const uint2* __restrict__ pair_o,
                        const int* __restrict__ boff_s, const int* __restrict__ boff_o,
                        int* __restrict__ off_s, int* __restrict__ off_o,
                        int* __restrict__ csr_s, int* __restrict__ csr_o)
{
  int b = blockIdx.x;
  int side = (b >= NB_S) ? 1 : 0;
  int lb = side ? b - NB_S : b;
  const uint2* pairs = side ? pair_o : pair_s;
  const int* boff = side ? boff_o : boff_s;
  int* off = side ? off_o : off_s;
  int* csr = side ? csr_o : csr_s;
  int SH = side ? SH_O : SH_S;
  int nd_tot = side ? N_OCC : N_SKILL;
  int d0 = lb << SH;
  int d1 = min(d0 + (1 << SH), nd_tot);
  int nd = d1 - d0;
  int p0 = boff[lb], p1 = boff[lb + 1];

  __shared__ int cntL[1 << SH_S];
  __shared__ int offL[1 << SH_S];
  __shared__ int ws[4];
  int t = threadIdx.x;
  cntL[t] = 0; cntL[t + 256] = 0;
  __syncthreads();
  // per-node histogram (LDS atomics only)
  for (int i = p0 + t; i < p1; i += 256)
    atomicAdd(&cntL[(int)pairs[i].y - d0], 1);
  __syncthreads();
  // exclusive scan over 512 LDS counters (2 per thread)
  int a0 = cntL[2 * t], a1 = cntL[2 * t + 1];
  int s = a0 + a1;
  int lane = t & 63, wv = t >> 6;
  int x = s;
  #pragma unroll
  for (int d = 1; d < 64; d <<= 1){ int u = __shfl_up(x, d, 64); if (lane >= d) x += u; }
  if (lane == 63) ws[wv] = x;
  __syncthreads();
  int woff = 0;
  for (int w = 0; w < wv; ++w) woff += ws[w];
  int excl = woff + x - s;
  offL[2 * t] = excl;
  offL[2 * t + 1] = excl + a0;
  __syncthreads();
  // node-level global offsets for this bucket's range
  for (int i = t; i < nd; i += 256) off[d0 + i] = p0 + offL[i];
  // reset LDS cursors, then scatter into contiguous csr window
  cntL[t] = 0; cntL[t + 256] = 0;
  __syncthreads();
  for (int i = p0 + t; i < p1; i += 256){
    uint2 pr = pairs[i];
    int d = (int)pr.y - d0;
    int p = p0 + offL[d] + atomicAdd(&cntL[d], 1);
    csr[p] = (int)pr.x;    // scattered only within one L2-resident ~50 KB window
  }
}

// ---------- segment mean: one wave per dst node, 128 bf16 feats ----------
__launch_bounds__(256)
__global__ void k_seg_mean(const unsigned short* __restrict__ feat,
                           const int* __restrict__ off, const int* __restrict__ csr,
                           unsigned short* __restrict__ out, int n_dst)
{
  int gw = (int)((blockIdx.x * blockDim.x + threadIdx.x) >> 6);
  if (gw >= n_dst) return;
  int lane = threadIdx.x & 63;
  int r = lane >> 4;
  int c = lane & 15;
  int beg = off[gw], end = off[gw + 1];
  float acc[8];
  #pragma unroll
  for (int j = 0; j < 8; ++j) acc[j] = 0.0f;
  for (int e = beg + r; e < end; e += 4){
    int s = csr[e];
    uint4 v = *(const uint4*)(feat + ((size_t)s << 7) + (c << 3));
    acc[0] += __uint_as_float(v.x << 16); acc[1] += __uint_as_float(v.x & 0xffff0000u);
    acc[2] += __uint_as_float(v.y << 16); acc[3] += __uint_as_float(v.y & 0xffff0000u);
    acc[4] += __uint_as_float(v.z << 16); acc[5] += __uint_as_float(v.z & 0xffff0000u);
    acc[6] += __uint_as_float(v.w << 16); acc[7] += __uint_as_float(v.w & 0xffff0000u);
  }
  #pragma unroll
  for (int j = 0; j < 8; ++j){
    acc[j] += __shfl_xor(acc[j], 16, 64);
    acc[j] += __shfl_xor(acc[j], 32, 64);
  }
  if (r == 0){
    int cnt = end - beg;
    float inv = 1.0f / (float)(cnt > 0 ? cnt : 1);
    uint4 o;
    o.x = f2bf_bits(acc[0] * inv) | (f2bf_bits(acc[1] * inv) << 16);
    o.y = f2bf_bits(acc[2] * inv) | (f2bf_bits(acc[3] * inv) << 16);
    o.z = f2bf_bits(acc[4] * inv) | (f2bf_bits(acc[5] * inv) << 16);
    o.w = f2bf_bits(acc[6] * inv) | (f2bf_bits(acc[7] * inv) << 16);
    *(uint4*)(out + ((size_t)gw << 7) + (c << 3)) = o;
  }
}

// ---------- fused GEMM: C = act(A1@W1 + [A2@W2] + bias) ----------
template<int NCOLS>
__launch_bounds__(256)
__global__ void k_gemm(const unsigned short* __restrict__ A1,
                       const unsigned short* __restrict__ W1T, int K1,
                       const unsigned short* __restrict__ A2,
                       const unsigned short* __restrict__ W2T, int K2,
                       const unsigned short* __restrict__ bias,
                       void* __restrict__ C, size_t c_off,
                       int M, int do_relu,
                       int to_wire, const int* __restrict__ wire_flag)
{
  constexpr int NT = NCOLS / 16;
  constexpr int MW = 2;
  const int lane = threadIdx.x & 63;
  const int wv   = threadIdx.x >> 6;
  const int q    = lane >> 4;
  const int mr   = lane & 15;
  const int m0   = blockIdx.x * (4 * MW * 16) + wv * (MW * 16);
  const int koff = q * 8;

  f32x4 acc[MW][NT];
  #pragma unroll
  for (int mw = 0; mw < MW; ++mw)
    #pragma unroll
    for (int nt = 0; nt < NT; ++nt)
      #pragma unroll
      for (int j = 0; j < 4; ++j) acc[mw][nt][j] = 0.0f;

  for (int k0 = 0; k0 < K1; k0 += 32){
    bf16x8 a[MW], b[NT];
    #pragma unroll
    for (int mw = 0; mw < MW; ++mw){
      int row = m0 + mw * 16 + mr;
      if (row < M){
        a[mw] = *(const bf16x8*)(A1 + (size_t)row * K1 + k0 + koff);
      } else {
        #pragma unroll
        for (int j = 0; j < 8; ++j) a[mw][j] = 0;
      }
    }
    #pragma unroll
    for (int nt = 0; nt < NT; ++nt)
      b[nt] = *(const bf16x8*)(W1T + (size_t)(nt * 16 + mr) * K1 + k0 + koff);
    #pragma unroll
    for (int mw = 0; mw < MW; ++mw)
      #pragma unroll
      for (int nt = 0; nt < NT; ++nt)
        acc[mw][nt] = __builtin_amdgcn_mfma_f32_16x16x32_bf16(a[mw], b[nt], acc[mw][nt], 0, 0, 0);
  }

  if (A2 != nullptr){
    for (int k0 = 0; k0 < K2; k0 += 32){
      bf16x8 a[MW], b[NT];
      #pragma unroll
      for (int mw = 0; mw < MW; ++mw){
        int row = m0 + mw * 16 + mr;
        if (row < M){
          a[mw] = *(const bf16x8*)(A2 + (size_t)row * K2 + k0 + koff);
        } else {
          #pragma unroll
          for (int j = 0; j < 8; ++j) a[mw][j] = 0;
        }
      }
      #pragma unroll
      for (int nt = 0; nt < NT; ++nt)
        b[nt] = *(const bf16x8*)(W2T + (size_t)(nt * 16 + mr) * K2 + k0 + koff);
      #pragma unroll
      for (int mw = 0; mw < MW; ++mw)
        #pragma unroll
        for (int nt = 0; nt < NT; ++nt)
          acc[mw][nt] = __builtin_amdgcn_mfma_f32_16x16x32_bf16(a[mw], b[nt], acc[mw][nt], 0, 0, 0);
    }
  }

  const int wf = to_wire ? *wire_flag : 0;   // 1 => write f32
  #pragma unroll
  for (int mw = 0; mw < MW; ++mw){
    #pragma unroll
    for (int nt = 0; nt < NT; ++nt){
      int col = nt * 16 + mr;
      float bv = bf2f(bias[col]);
      #pragma unroll
      for (int r4 = 0; r4 < 4; ++r4){
        int row = m0 + mw * 16 + q * 4 + r4;
        if (row < M){
          float v = acc[mw][nt][r4] + bv;
          if (do_relu) v = fmaxf(v, 0.0f);
          size_t idx = c_off + (size_t)row * NCOLS + col;
          if (wf) ((float*)C)[idx] = v;
          else    ((unsigned short*)C)[idx] = f2bf(v);
        }
      }
    }
  }
}

extern "C" void kernel_launch(void* const* d_in, const int* in_sizes, int n_in,
                              void* d_out, int out_size, void* d_ws, size_t ws_size,
                              hipStream_t stream)
{
  const void* raw[20];
  for (int i = 0; i < 20; ++i) raw[i] = d_in[i];
  const int* edge_occ   = (const int*)d_in[2];
  const int* edge_skill = (const int*)d_in[3];

  char* ws = (char*)d_ws;
  size_t off = 0;
  auto alloc = [&](size_t bytes) -> char* {
    char* p = ws + off;
    off = (off + bytes + 255) & ~(size_t)255;
    return p;
  };

  int* wire_flag = (int*)alloc(4);

  // canonical bf16 copies of all float tensors (18 of them)
  static const int cn[NT_CONV] = {
    N_OCC * D_IN, N_SKILL * D_IN,                // x_occ, x_skill
    D_IN * HID, HID, D_IN * HID, HID,            // pW_occ, pb_occ, pW_skill, pb_skill
    HID * HID, HID, HID * HID,                   // c1_os_Wl, bl, Wr
    HID * HID, HID, HID * HID,                   // c1_so_Wl, bl, Wr
    HID * OUT_F, OUT_F, HID * OUT_F,             // c2_os_Wl, bl, Wr
    HID * OUT_F, OUT_F, HID * OUT_F              // c2_so_Wl, bl, Wr
  };
  static const int raw_idx[NT_CONV] = {0,1, 4,5,6,7, 8,9,10, 11,12,13, 14,15,16, 17,18,19};
  unsigned short* can[NT_CONV];
  for (int i = 0; i < NT_CONV; ++i) can[i] = (unsigned short*)alloc((size_t)cn[i] * 2);

  ConvTable ct;
  ct.blk_off[0] = 0;
  for (int i = 0; i < NT_CONV; ++i){
    ct.src[i] = raw[raw_idx[i]];
    ct.dst[i] = can[i];
    ct.n[i]   = cn[i];
    ct.blk_off[i + 1] = ct.blk_off[i] + (cn[i] + 2047) / 2048;
  }
  const int conv_blocks = ct.blk_off[NT_CONV];

  const unsigned short* c_xocc   = can[0];
  const unsigned short* c_xskill = can[1];
  const unsigned short* c_pWo = can[2],  *c_pbo = can[3];
  const unsigned short* c_pWs = can[4],  *c_pbs = can[5];
  const unsigned short* c1osWl = can[6], *c1osbl = can[7], *c1osWr = can[8];
  const unsigned short* c1soWl = can[9], *c1sobl = can[10], *c1soWr = can[11];
  const unsigned short* c2osWl = can[12], *c2osbl = can[13], *c2osWr = can[14];
  const unsigned short* c2soWl = can[15], *c2sobl = can[16], *c2soWr = can[17];

  // transposed weights
  unsigned short* wt_pocc   = (unsigned short*)alloc(32768 * 2);
  unsigned short* wt_pskill = (unsigned short*)alloc(32768 * 2);
  unsigned short* wt_c1osWl = (unsigned short*)alloc(16384 * 2);
  unsigned short* wt_c1osWr = (unsigned short*)alloc(16384 * 2);
  unsigned short* wt_c1soWl = (unsigned short*)alloc(16384 * 2);
  unsigned short* wt_c1soWr = (unsigned short*)alloc(16384 * 2);
  unsigned short* wt_c2osWl = (unsigned short*)alloc(8192 * 2);
  unsigned short* wt_c2osWr = (unsigned short*)alloc(8192 * 2);
  unsigned short* wt_c2soWl = (unsigned short*)alloc(8192 * 2);
  unsigned short* wt_c2soWr = (unsigned short*)alloc(8192 * 2);

  // zero-initialized region: bucket counts + bucket cursors (no node-level counters)
  char* zero_base = alloc((size_t)(2 * (NB_S + NB_O)) * 4);
  int* bkcnt_s = (int*)zero_base;
  int* bkcnt_o = bkcnt_s + NB_S;
  int* bcur_s  = bkcnt_o + NB_O;
  int* bcur_o  = bcur_s + NB_S;
  size_t zero_bytes = (size_t)(2 * (NB_S + NB_O)) * 4;

  int* boff_s = (int*)alloc((NB_S + 1) * 4);
  int* boff_o = (int*)alloc((NB_O + 1) * 4);
  int* off_s = (int*)alloc((N_SKILL + 1) * 4);
  int* off_o = (int*)alloc((N_OCC + 1) * 4);
  int* csr_s = (int*)alloc((size_t)N_EDGE * 4);
  int* csr_o = (int*)alloc((size_t)N_EDGE * 4);
  uint2* pair_s = (uint2*)alloc((size_t)N_EDGE * 8);
  uint2* pair_o = (uint2*)alloc((size_t)N_EDGE * 8);

  unsigned short* h_occ   = (unsigned short*)alloc((size_t)N_OCC * HID * 2);
  unsigned short* h_skill = (unsigned short*)alloc((size_t)N_SKILL * HID * 2);
  unsigned short* mean_s  = (unsigned short*)alloc((size_t)N_SKILL * HID * 2);
  unsigned short* mean_o  = (unsigned short*)alloc((size_t)N_OCC * HID * 2);
  unsigned short* s1      = (unsigned short*)alloc((size_t)N_SKILL * HID * 2);
  unsigned short* o1      = (unsigned short*)alloc((size_t)N_OCC * HID * 2);

  const int G_OCC  = (N_OCC + 127) / 128;
  const int G_SKL  = (N_SKILL + 127) / 128;
  const int SM_SKL = (N_SKILL + 3) / 4;
  const int SM_OCC = (N_OCC + 3) / 4;

  hipMemsetAsync(zero_base, 0, zero_bytes, stream);

  k_detect<<<1, 64, 0, stream>>>((const unsigned short*)raw[0], wire_flag);
  k_convert<<<conv_blocks, 256, 0, stream>>>(ct, wire_flag);

  k_transpose_all<<<640, 256, 0, stream>>>(
      c_pWo, wt_pocc, c_pWs, wt_pskill,
      c1osWl, wt_c1osWl, c1osWr, wt_c1osWr,
      c1soWl, wt_c1soWl, c1soWr, wt_c1soWr,
      c2osWl, wt_c2osWl, c2osWr, wt_c2osWr,
      c2soWl, wt_c2soWl, c2soWr, wt_c2soWr);

  // CSR build: bucket histogram -> bucket scan -> bin pairs -> per-bucket build
  k_bincount<<<2 * BIN_BLKS, 256, 0, stream>>>(edge_occ, edge_skill, bkcnt_s, bkcnt_o);
  k_bscan<<<1, 128, 0, stream>>>(bkcnt_s, bkcnt_o, boff_s, boff_o, off_s, off_o);
  k_bin<<<2 * BIN_BLKS, 256, 0, stream>>>(edge_occ, edge_skill, boff_s, boff_o,
                                          bcur_s, bcur_o, pair_s, pair_o);
  k_build<<<NB_S + NB_O, 256, 0, stream>>>(pair_s, pair_o, boff_s, boff_o,
                                           off_s, off_o, csr_s, csr_o);

  // input projections + relu
  k_gemm<128><<<G_OCC, 256, 0, stream>>>(c_xocc, wt_pocc, D_IN, nullptr, nullptr, 0,
                                         c_pbo, h_occ, 0, N_OCC, 1, 0, wire_flag);
  k_gemm<128><<<G_SKL, 256, 0, stream>>>(c_xskill, wt_pskill, D_IN, nullptr, nullptr, 0,
                                         c_pbs, h_skill, 0, N_SKILL, 1, 0, wire_flag);

  // conv1 aggregation
  k_seg_mean<<<SM_SKL, 256, 0, stream>>>(h_occ, off_s, csr_s, mean_s, N_SKILL);
  k_seg_mean<<<SM_OCC, 256, 0, stream>>>(h_skill, off_o, csr_o, mean_o, N_OCC);

  // conv1 linear
  k_gemm<128><<<G_SKL, 256, 0, stream>>>(mean_s, wt_c1osWl, HID, h_skill, wt_c1osWr, HID,
                                         c1osbl, s1, 0, N_SKILL, 1, 0, wire_flag);
  k_gemm<128><<<G_OCC, 256, 0, stream>>>(mean_o, wt_c1soWl, HID, h_occ, wt_c1soWr, HID,
                                         c1sobl, o1, 0, N_OCC, 1, 0, wire_flag);

  // conv2 aggregation
  k_seg_mean<<<SM_SKL, 256, 0, stream>>>(o1, off_s, csr_s, mean_s, N_SKILL);
  k_seg_mean<<<SM_OCC, 256, 0, stream>>>(s1, off_o, csr_o, mean_o, N_OCC);

  // conv2 linear -> d_out (o2 at element offset 0, s2 after it)
  k_gemm<64><<<G_SKL, 256, 0, stream>>>(mean_s, wt_c2osWl, HID, s1, wt_c2osWr, HID,
                                        c2osbl, d_out, (size_t)N_OCC * OUT_F, N_SKILL, 0, 1, wire_flag);
  k_gemm<64><<<G_OCC, 256, 0, stream>>>(mean_o, wt_c2soWl, HID, o1, wt_c2soWr, HID,
                                        c2sobl, d_out, 0, N_OCC, 0, 1, wire_flag);
}

// Round 3
// 408.002 us; speedup vs baseline: 1.4135x; 1.0117x over previous
//
#include <hip/hip_runtime.h>

#define N_OCC   20000
#define N_SKILL 50000
#define N_EDGE  600000
#define D_IN    256
#define HID     128
#define OUT_F   64

typedef short bf16x8 __attribute__((ext_vector_type(8)));
typedef float f32x4  __attribute__((ext_vector_type(4)));

__device__ __forceinline__ float bf2f(unsigned short u){
  return __uint_as_float(((unsigned)u) << 16);
}
__device__ __forceinline__ unsigned f2bf_bits(float f){
  unsigned i = __float_as_uint(f);
  return (i + 0x7fffu + ((i >> 16) & 1u)) >> 16;   // RNE
}
__device__ __forceinline__ unsigned f2bf_bits_u(unsigned i){
  return (i + 0x7fffu + ((i >> 16) & 1u)) >> 16;   // RNE from raw f32 bits
}
__device__ __forceinline__ unsigned short f2bf(float f){ return (unsigned short)f2bf_bits(f); }

// ---------- wire-dtype detection ----------
__global__ void k_detect(const unsigned short* __restrict__ x, int* __restrict__ flag){
  int lane = threadIdx.x & 63;
  int cnt = 0;
  for (int i = lane; i < 1024; i += 64){
    unsigned e = ((unsigned)x[i] >> 7) & 0xFFu;
    if (e >= 0xE0u) cnt++;
  }
  #pragma unroll
  for (int s = 1; s < 64; s <<= 1) cnt += __shfl_xor(cnt, s, 64);
  if (lane == 0) *flag = (cnt >= 8) ? 1 : 0;   // 1 => wire is f32
}

// ---------- canonicalize WEIGHT tensors to bf16 (x handled in-GEMM) ----------
#define NT_CONV 16
struct ConvTable {
  const void*     src[NT_CONV];
  unsigned short* dst[NT_CONV];
  int             n[NT_CONV];
  int             blk_off[NT_CONV + 1];   // cumulative blocks (2048 elems/block)
};

__global__ void k_convert(ConvTable t, const int* __restrict__ flag){
  int isf32 = *flag;
  int b = blockIdx.x;
  int ti = 0;
  while (ti < NT_CONV - 1 && b >= t.blk_off[ti + 1]) ti++;
  int lb = b - t.blk_off[ti];
  int i = (lb * 256 + (int)threadIdx.x) * 8;     // element index (8 per thread)
  if (i >= t.n[ti]) return;
  unsigned short* dst = t.dst[ti];
  if (isf32){
    const float* s = (const float*)t.src[ti];
    uint4 lo = *(const uint4*)(s + i);
    uint4 hi = *(const uint4*)(s + i + 4);
    uint4 o;
    o.x = f2bf_bits_u(lo.x) | (f2bf_bits_u(lo.y) << 16);
    o.y = f2bf_bits_u(lo.z) | (f2bf_bits_u(lo.w) << 16);
    o.z = f2bf_bits_u(hi.x) | (f2bf_bits_u(hi.y) << 16);
    o.w = f2bf_bits_u(hi.z) | (f2bf_bits_u(hi.w) << 16);
    *(uint4*)(dst + i) = o;
  } else {
    *(uint4*)(dst + i) = *(const uint4*)((const unsigned short*)t.src[ti] + i);
  }
}

// ---------- transpose weight matrices W[K][N] -> WT[N][K] ----------
// conv2 weights are transposed into COMBINED [Wl | Wr] blocks via dst offsets.
__global__ void k_transpose_all(
    const unsigned short* pWo, unsigned short* tWo,   // 256x128
    const unsigned short* pWs, unsigned short* tWs,   // 256x128
    const unsigned short* w2,  unsigned short* t2,    // 128x128
    const unsigned short* w3,  unsigned short* t3,
    const unsigned short* w4,  unsigned short* t4,
    const unsigned short* w5,  unsigned short* t5,
    const unsigned short* w6,  unsigned short* t6,    // 128x64
    const unsigned short* w7,  unsigned short* t7,
    const unsigned short* w8,  unsigned short* t8,
    const unsigned short* w9,  unsigned short* t9)
{
  int idx = blockIdx.x * blockDim.x + threadIdx.x;
  const unsigned short* in; unsigned short* out; int K, N, base;
  if      (idx <  32768){ in=pWo; out=tWo; K=256; N=128; base=0; }
  else if (idx <  65536){ in=pWs; out=tWs; K=256; N=128; base=32768; }
  else if (idx <  81920){ in=w2;  out=t2;  K=128; N=128; base=65536; }
  else if (idx <  98304){ in=w3;  out=t3;  K=128; N=128; base=81920; }
  else if (idx < 114688){ in=w4;  out=t4;  K=128; N=128; base=98304; }
  else if (idx < 131072){ in=w5;  out=t5;  K=128; N=128; base=114688; }
  else if (idx < 139264){ in=w6;  out=t6;  K=128; N=64;  base=131072; }
  else if (idx < 147456){ in=w7;  out=t7;  K=128; N=64;  base=139264; }
  else if (idx < 155648){ in=w8;  out=t8;  K=128; N=64;  base=147456; }
  else if (idx < 163840){ in=w9;  out=t9;  K=128; N=64;  base=155648; }
  else return;
  int li = idx - base;
  int k = li / N, n = li - k * N;
  out[n * K + k] = in[li];
}

// ---------- CSR build: bucket counting sort, no node-level global atomics ----------
#define EPB      4096
#define BIN_BLKS ((N_EDGE + EPB - 1) / EPB)         // 147
#define SH_S 9
#define SH_O 8
#define NB_S ((N_SKILL + (1 << SH_S) - 1) >> SH_S)  // 98
#define NB_O ((N_OCC   + (1 << SH_O) - 1) >> SH_O)  // 79

__launch_bounds__(256)
__global__ void k_bincount(const int* __restrict__ eo, const int* __restrict__ es,
                           int* __restrict__ bkcnt_s, int* __restrict__ bkcnt_o)
{
  int b = blockIdx.x;
  int side = (b >= BIN_BLKS) ? 1 : 0;
  int lb = side ? b - BIN_BLKS : b;
  const int* dste = side ? eo : es;
  int* bkcnt = side ? bkcnt_o : bkcnt_s;
  const int NB = side ? NB_O : NB_S;
  const int SH = side ? SH_O : SH_S;
  __shared__ int cntL[NB_S];
  for (int i = threadIdx.x; i < NB; i += 256) cntL[i] = 0;
  __syncthreads();
  int e0 = lb * EPB, e1 = min(e0 + EPB, N_EDGE);
  for (int e = e0 + threadIdx.x; e < e1; e += 256)
    atomicAdd(&cntL[dste[e] >> SH], 1);
  __syncthreads();
  for (int i = threadIdx.x; i < NB; i += 256)
    if (cntL[i]) atomicAdd(&bkcnt[i], cntL[i]);
}

__global__ void k_bscan(const int* __restrict__ bkcnt_s, const int* __restrict__ bkcnt_o,
                        int* __restrict__ boff_s, int* __restrict__ boff_o,
                        int* __restrict__ off_s, int* __restrict__ off_o)
{
  __shared__ int sc[128];
  int t = threadIdx.x;   // 128 threads
  int v = (t < NB_S) ? bkcnt_s[t] : 0;
  sc[t] = v;
  __syncthreads();
  for (int d = 1; d < 128; d <<= 1){
    int u = (t >= d) ? sc[t - d] : 0;
    __syncthreads();
    sc[t] += u;
    __syncthreads();
  }
  if (t < NB_S) boff_s[t] = sc[t] - v;
  if (t == 0){ boff_s[NB_S] = N_EDGE; off_s[N_SKILL] = N_EDGE; }
  __syncthreads();
  int v2 = (t < NB_O) ? bkcnt_o[t] : 0;
  sc[t] = v2;
  __syncthreads();
  for (int d = 1; d < 128; d <<= 1){
    int u = (t >= d) ? sc[t - d] : 0;
    __syncthreads();
    sc[t] += u;
    __syncthreads();
  }
  if (t < NB_O) boff_o[t] = sc[t] - v2;
  if (t == 0){ boff_o[NB_O] = N_EDGE; off_o[N_OCC] = N_EDGE; }
}

// packed pair: (local_dst << 16) | src   (src < 65536, local_dst < 512)
__launch_bounds__(256)
__global__ void k_bin(const int* __restrict__ eo, const int* __restrict__ es,
                      const int* __restrict__ boff_s, const int* __restrict__ boff_o,
                      int* __restrict__ bcur_s, int* __restrict__ bcur_o,
                      unsigned* __restrict__ pair_s, unsigned* __restrict__ pair_o)
{
  int b = blockIdx.x;
  int side = (b >= BIN_BLKS) ? 1 : 0;
  int lb = side ? b - BIN_BLKS : b;
  const int* dste = side ? eo : es;
  const int* srce = side ? es : eo;
  const int* boff = side ? boff_o : boff_s;
  int* bcur       = side ? bcur_o : bcur_s;
  unsigned* pairs = side ? pair_o : pair_s;
  const int NB = side ? NB_O : NB_S;
  const int SH = side ? SH_O : SH_S;

  __shared__ int cntL[NB_S], gbaseL[NB_S], lbaseL[NB_S], runL[NB_S];
  __shared__ int sc[128];
  __shared__ unsigned stage[EPB];   // 16 KB
  __shared__ int gpos[EPB];         // 16 KB

  int e0 = lb * EPB;
  int e1 = min(e0 + EPB, N_EDGE);

  for (int i = threadIdx.x; i < NB; i += 256){ cntL[i] = 0; runL[i] = 0; }
  __syncthreads();
  for (int e = e0 + threadIdx.x; e < e1; e += 256)
    atomicAdd(&cntL[dste[e] >> SH], 1);
  __syncthreads();
  if (threadIdx.x < 128) sc[threadIdx.x] = (threadIdx.x < NB) ? cntL[threadIdx.x] : 0;
  __syncthreads();
  for (int d = 1; d < 128; d <<= 1){
    int v = 0;
    if (threadIdx.x < 128 && threadIdx.x >= d) v = sc[threadIdx.x - d];
    __syncthreads();
    if (threadIdx.x < 128) sc[threadIdx.x] += v;
    __syncthreads();
  }
  if (threadIdx.x < NB){
    int c = cntL[threadIdx.x];
    lbaseL[threadIdx.x] = sc[threadIdx.x] - c;
    gbaseL[threadIdx.x] = boff[threadIdx.x] + atomicAdd(&bcur[threadIdx.x], c);
  }
  __syncthreads();
  for (int e = e0 + threadIdx.x; e < e1; e += 256){
    int d = dste[e], s = srce[e];
    int bk = d >> SH;
    int r = atomicAdd(&runL[bk], 1);
    int lp = lbaseL[bk] + r;
    stage[lp] = ((unsigned)(d & ((1 << SH) - 1)) << 16) | (unsigned)s;
    gpos[lp] = gbaseL[bk] + r;
  }
  __syncthreads();
  int tot = e1 - e0;
  for (int i = threadIdx.x; i < tot; i += 256)
    pairs[gpos[i]] = stage[i];     // consecutive within each bucket run -> coalesced
}

__launch_bounds__(256)
__global__ void k_build(const unsigned* __restrict__ pair_s, const unsigned* __restrict__ pair_o,
                        const int* __restrict__ boff_s, const int* __restrict__ boff_o,
                        int* __restrict__ off_s, int* __restrict__ off_o,
                        int* __restrict__ csr_s, int* __restrict__ csr_o)
{
  int b = blockIdx.x;
  int side = (b >= NB_S) ? 1 : 0;
  int lb = side ? b - NB_S : b;
  const unsigned* pairs = side ? pair_o : pair_s;
  const int* boff = side ? boff_o : boff_s;
  int* off = side ? off_o : off_s;
  int* csr = side ? csr_o : csr_s;
  int SH = side ? SH_O : SH_S;
  int nd_tot = side ? N_OCC : N_SKILL;
  int d0 = lb << SH;
  int d1 = min(d0 + (1 << SH), nd_tot);
  int nd = d1 - d0;
  int p0 = boff[lb], p1 = boff[lb + 1];

  __shared__ int cntL[1 << SH_S];
  __shared__ int offL[1 << SH_S];
  __shared__ int ws[4];
  int t = threadIdx.x;
  cntL[t] = 0; cntL[t + 256] = 0;
  __syncthreads();
  for (int i = p0 + t; i < p1; i += 256)
    atomicAdd(&cntL[pairs[i] >> 16], 1);
  __syncthreads();
  int a0 = cntL[2 * t], a1 = cntL[2 * t + 1];
  int s = a0 + a1;
  int lane = t & 63, wv = t >> 6;
  int x = s;
  #pragma unroll
  for (int d = 1; d < 64; d <<= 1){ int u = __shfl_up(x, d, 64); if (lane >= d) x += u; }
  if (lane == 63) ws[wv] = x;
  __syncthreads();
  int woff = 0;
  for (int w = 0; w < wv; ++w) woff += ws[w];
  int excl = woff + x - s;
  offL[2 * t] = excl;
  offL[2 * t + 1] = excl + a0;
  __syncthreads();
  for (int i = t; i < nd; i += 256) off[d0 + i] = p0 + offL[i];
  cntL[t] = 0; cntL[t + 256] = 0;
  __syncthreads();
  for (int i = p0 + t; i < p1; i += 256){
    unsigned pr = pairs[i];
    int d = (int)(pr >> 16);
    int p = p0 + offL[d] + atomicAdd(&cntL[d], 1);
    csr[p] = (int)(pr & 0xFFFFu);   // scattered only within one L2-resident window
  }
}

// ---------- segment mean: one wave per dst node, 128 bf16 feats ----------
__launch_bounds__(256)
__global__ void k_seg_mean(const unsigned short* __restrict__ feat,
                           const int* __restrict__ off, const int* __restrict__ csr,
                           unsigned short* __restrict__ out, int n_dst)
{
  int gw = (int)((blockIdx.x * blockDim.x + threadIdx.x) >> 6);
  if (gw >= n_dst) return;
  int lane = threadIdx.x & 63;
  int r = lane >> 4;
  int c = lane & 15;
  int beg = off[gw], end = off[gw + 1];
  float acc[8];
  #pragma unroll
  for (int j = 0; j < 8; ++j) acc[j] = 0.0f;
  for (int e = beg + r; e < end; e += 4){
    int s = csr[e];
    uint4 v = *(const uint4*)(feat + ((size_t)s << 7) + (c << 3));
    acc[0] += __uint_as_float(v.x << 16); acc[1] += __uint_as_float(v.x & 0xffff0000u);
    acc[2] += __uint_as_float(v.y << 16); acc[3] += __uint_as_float(v.y & 0xffff0000u);
    acc[4] += __uint_as_float(v.z << 16); acc[5] += __uint_as_float(v.z & 0xffff0000u);
    acc[6] += __uint_as_float(v.w << 16); acc[7] += __uint_as_float(v.w & 0xffff0000u);
  }
  #pragma unroll
  for (int j = 0; j < 8; ++j){
    acc[j] += __shfl_xor(acc[j], 16, 64);
    acc[j] += __shfl_xor(acc[j], 32, 64);
  }
  if (r == 0){
    int cnt = end - beg;
    float inv = 1.0f / (float)(cnt > 0 ? cnt : 1);
    uint4 o;
    o.x = f2bf_bits(acc[0] * inv) | (f2bf_bits(acc[1] * inv) << 16);
    o.y = f2bf_bits(acc[2] * inv) | (f2bf_bits(acc[3] * inv) << 16);
    o.z = f2bf_bits(acc[4] * inv) | (f2bf_bits(acc[5] * inv) << 16);
    o.w = f2bf_bits(acc[6] * inv) | (f2bf_bits(acc[7] * inv) << 16);
    *(uint4*)(out + ((size_t)gw << 7) + (c << 3)) = o;
  }
}

// ---------- conv2 fused: out = mean_gather(Pg[:,0:64]) + Ps[d,64:128] + bias ----------
__launch_bounds__(256)
__global__ void k_seg_out(const unsigned short* __restrict__ Pg,   // [*,128] gather cols 0..63
                          const unsigned short* __restrict__ Ps,   // [n_dst,128] self cols 64..127
                          const int* __restrict__ off, const int* __restrict__ csr,
                          const unsigned short* __restrict__ bias, // [64]
                          void* __restrict__ out, size_t o_off, int n_dst,
                          const int* __restrict__ wire_flag)
{
  int gw = (int)((blockIdx.x * blockDim.x + threadIdx.x) >> 6);
  if (gw >= n_dst) return;
  int lane = threadIdx.x & 63;
  int r = lane >> 3;          // 8 edge groups
  int c = lane & 7;           // 8 chunks of 8 bf16 = 64 feats
  int beg = off[gw], end = off[gw + 1];
  float acc[8];
  #pragma unroll
  for (int j = 0; j < 8; ++j) acc[j] = 0.0f;
  for (int e = beg + r; e < end; e += 8){
    int s = csr[e];
    uint4 v = *(const uint4*)(Pg + ((size_t)s << 7) + (c << 3));
    acc[0] += __uint_as_float(v.x << 16); acc[1] += __uint_as_float(v.x & 0xffff0000u);
    acc[2] += __uint_as_float(v.y << 16); acc[3] += __uint_as_float(v.y & 0xffff0000u);
    acc[4] += __uint_as_float(v.z << 16); acc[5] += __uint_as_float(v.z & 0xffff0000u);
    acc[6] += __uint_as_float(v.w << 16); acc[7] += __uint_as_float(v.w & 0xffff0000u);
  }
  #pragma unroll
  for (int j = 0; j < 8; ++j){
    acc[j] += __shfl_xor(acc[j], 8, 64);
    acc[j] += __shfl_xor(acc[j], 16, 64);
    acc[j] += __shfl_xor(acc[j], 32, 64);
  }
  if (r == 0){
    int cnt = end - beg;
    float inv = 1.0f / (float)(cnt > 0 ? cnt : 1);
    uint4 sv = *(const uint4*)(Ps + ((size_t)gw << 7) + 64 + (c << 3));
    uint4 bv = *(const uint4*)(bias + (c << 3));
    float o0 = acc[0] * inv + __uint_as_float(sv.x << 16)        + __uint_as_float(bv.x << 16);
    float o1 = acc[1] * inv + __uint_as_float(sv.x & 0xffff0000u) + __uint_as_float(bv.x & 0xffff0000u);
    float o2 = acc[2] * inv + __uint_as_float(sv.y << 16)        + __uint_as_float(bv.y << 16);
    float o3 = acc[3] * inv + __uint_as_float(sv.y & 0xffff0000u) + __uint_as_float(bv.y & 0xffff0000u);
    float o4 = acc[4] * inv + __uint_as_float(sv.z << 16)        + __uint_as_float(bv.z << 16);
    float o5 = acc[5] * inv + __uint_as_float(sv.z & 0xffff0000u) + __uint_as_float(bv.z & 0xffff0000u);
    float o6 = acc[6] * inv + __uint_as_float(sv.w << 16)        + __uint_as_float(bv.w << 16);
    float o7 = acc[7] * inv + __uint_as_float(sv.w & 0xffff0000u) + __uint_as_float(bv.w & 0xffff0000u);
    size_t eoff = o_off + (size_t)gw * 64 + (c << 3);
    if (*wire_flag){
      float* op = (float*)out + eoff;
      uint4 w0, w1;
      w0.x = __float_as_uint(o0); w0.y = __float_as_uint(o1);
      w0.z = __float_as_uint(o2); w0.w = __float_as_uint(o3);
      w1.x = __float_as_uint(o4); w1.y = __float_as_uint(o5);
      w1.z = __float_as_uint(o6); w1.w = __float_as_uint(o7);
      *(uint4*)op = w0;
      *(uint4*)(op + 4) = w1;
    } else {
      unsigned short* op = (unsigned short*)out + eoff;
      uint4 w;
      w.x = f2bf_bits(o0) | (f2bf_bits(o1) << 16);
      w.y = f2bf_bits(o2) | (f2bf_bits(o3) << 16);
      w.z = f2bf_bits(o4) | (f2bf_bits(o5) << 16);
      w.w = f2bf_bits(o6) | (f2bf_bits(o7) << 16);
      *(uint4*)op = w;
    }
  }
}

// ---------- fused GEMM: C = act(A1@W1 + [A2@W2] + bias) ----------
// a_from_wire: A1 is the raw wire tensor (f32 if *wire_flag else bf16)
template<int NCOLS>
__launch_bounds__(256)
__global__ void k_gemm(const unsigned short* __restrict__ A1,
                       const unsigned short* __restrict__ W1T, int K1,
                       const unsigned short* __restrict__ A2,
                       const unsigned short* __restrict__ W2T, int K2,
                       const unsigned short* __restrict__ bias,
                       void* __restrict__ C, size_t c_off,
                       int M, int do_relu,
                       int to_wire, const int* __restrict__ wire_flag,
                       int a_from_wire)
{
  constexpr int NT = NCOLS / 16;
  constexpr int MW = 2;
  const int lane = threadIdx.x & 63;
  const int wv   = threadIdx.x >> 6;
  const int q    = lane >> 4;
  const int mr   = lane & 15;
  const int m0   = blockIdx.x * (4 * MW * 16) + wv * (MW * 16);
  const int koff = q * 8;
  const int awf  = a_from_wire ? *wire_flag : 0;   // 1 => A1 is f32

  f32x4 acc[MW][NT];
  #pragma unroll
  for (int mw = 0; mw < MW; ++mw)
    #pragma unroll
    for (int nt = 0; nt < NT; ++nt)
      #pragma unroll
      for (int j = 0; j < 4; ++j) acc[mw][nt][j] = 0.0f;

  for (int k0 = 0; k0 < K1; k0 += 32){
    bf16x8 a[MW], b[NT];
    #pragma unroll
    for (int mw = 0; mw < MW; ++mw){
      int row = m0 + mw * 16 + mr;
      if (row < M){
        if (awf){
          const float* ar = (const float*)A1 + (size_t)row * K1 + k0 + koff;
          uint4 lo = *(const uint4*)ar;
          uint4 hi = *(const uint4*)(ar + 4);
          union { bf16x8 v; uint4 u; } cv;
          cv.u.x = f2bf_bits_u(lo.x) | (f2bf_bits_u(lo.y) << 16);
          cv.u.y = f2bf_bits_u(lo.z) | (f2bf_bits_u(lo.w) << 16);
          cv.u.z = f2bf_bits_u(hi.x) | (f2bf_bits_u(hi.y) << 16);
          cv.u.w = f2bf_bits_u(hi.z) | (f2bf_bits_u(hi.w) << 16);
          a[mw] = cv.v;
        } else {
          a[mw] = *(const bf16x8*)(A1 + (size_t)row * K1 + k0 + koff);
        }
      } else {
        #pragma unroll
        for (int j = 0; j < 8; ++j) a[mw][j] = 0;
      }
    }
    #pragma unroll
    for (int nt = 0; nt < NT; ++nt)
      b[nt] = *(const bf16x8*)(W1T + (size_t)(nt * 16 + mr) * K1 + k0 + koff);
    #pragma unroll
    for (int mw = 0; mw < MW; ++mw)
      #pragma unroll
      for (int nt = 0; nt < NT; ++nt)
        acc[mw][nt] = __builtin_amdgcn_mfma_f32_16x16x32_bf16(a[mw], b[nt], acc[mw][nt], 0, 0, 0);
  }

  if (A2 != nullptr){
    for (int k0 = 0; k0 < K2; k0 += 32){
      bf16x8 a[MW], b[NT];
      #pragma unroll
      for (int mw = 0; mw < MW; ++mw){
        int row = m0 + mw * 16 + mr;
        if (row < M){
          a[mw] = *(const bf16x8*)(A2 + (size_t)row * K2 + k0 + koff);
        } else {
          #pragma unroll
          for (int j = 0; j < 8; ++j) a[mw][j] = 0;
        }
      }
      #pragma unroll
      for (int nt = 0; nt < NT; ++nt)
        b[nt] = *(const bf16x8*)(W2T + (size_t)(nt * 16 + mr) * K2 + k0 + koff);
      #pragma unroll
      for (int mw = 0; mw < MW; ++mw)
        #pragma unroll
        for (int nt = 0; nt < NT; ++nt)
          acc[mw][nt] = __builtin_amdgcn_mfma_f32_16x16x32_bf16(a[mw], b[nt], acc[mw][nt], 0, 0, 0);
    }
  }

  const int wf = to_wire ? *wire_flag : 0;   // 1 => write f32
  #pragma unroll
  for (int mw = 0; mw < MW; ++mw){
    #pragma unroll
    for (int nt = 0; nt < NT; ++nt){
      int col = nt * 16 + mr;
      float bv = bf2f(bias[col]);
      #pragma unroll
      for (int r4 = 0; r4 < 4; ++r4){
        int row = m0 + mw * 16 + q * 4 + r4;
        if (row < M){
          float v = acc[mw][nt][r4] + bv;
          if (do_relu) v = fmaxf(v, 0.0f);
          size_t idx = c_off + (size_t)row * NCOLS + col;
          if (wf) ((float*)C)[idx] = v;
          else    ((unsigned short*)C)[idx] = f2bf(v);
        }
      }
    }
  }
}

extern "C" void kernel_launch(void* const* d_in, const int* in_sizes, int n_in,
                              void* d_out, int out_size, void* d_ws, size_t ws_size,
                              hipStream_t stream)
{
  const void* raw[20];
  for (int i = 0; i < 20; ++i) raw[i] = d_in[i];
  const int* edge_occ   = (const int*)d_in[2];
  const int* edge_skill = (const int*)d_in[3];

  char* ws = (char*)d_ws;
  size_t off = 0;
  auto alloc = [&](size_t bytes) -> char* {
    char* p = ws + off;
    off = (off + bytes + 255) & ~(size_t)255;
    return p;
  };

  int* wire_flag = (int*)alloc(4);

  // canonical bf16 copies of the 16 WEIGHT tensors (x stays on the wire)
  static const int cn[NT_CONV] = {
    D_IN * HID, HID, D_IN * HID, HID,            // pW_occ, pb_occ, pW_skill, pb_skill
    HID * HID, HID, HID * HID,                   // c1_os_Wl, bl, Wr
    HID * HID, HID, HID * HID,                   // c1_so_Wl, bl, Wr
    HID * OUT_F, OUT_F, HID * OUT_F,             // c2_os_Wl, bl, Wr
    HID * OUT_F, OUT_F, HID * OUT_F              // c2_so_Wl, bl, Wr
  };
  static const int raw_idx[NT_CONV] = {4,5,6,7, 8,9,10, 11,12,13, 14,15,16, 17,18,19};
  unsigned short* can[NT_CONV];
  for (int i = 0; i < NT_CONV; ++i) can[i] = (unsigned short*)alloc((size_t)cn[i] * 2);

  ConvTable ct;
  ct.blk_off[0] = 0;
  for (int i = 0; i < NT_CONV; ++i){
    ct.src[i] = raw[raw_idx[i]];
    ct.dst[i] = can[i];
    ct.n[i]   = cn[i];
    ct.blk_off[i + 1] = ct.blk_off[i] + (cn[i] + 2047) / 2048;
  }
  const int conv_blocks = ct.blk_off[NT_CONV];

  const unsigned short* c_pWo = can[0],  *c_pbo = can[1];
  const unsigned short* c_pWs = can[2],  *c_pbs = can[3];
  const unsigned short* c1osWl = can[4], *c1osbl = can[5], *c1osWr = can[6];
  const unsigned short* c1soWl = can[7], *c1sobl = can[8], *c1soWr = can[9];
  const unsigned short* c2osWl = can[10], *c2osbl = can[11], *c2osWr = can[12];
  const unsigned short* c2soWl = can[13], *c2sobl = can[14], *c2soWr = can[15];

  // transposed weights; conv2 weights land in combined [Wl | Wr] 128x128 blocks:
  //   comb_occ  rows 0..63 = c2_os_Wl^T, rows 64..127 = c2_so_Wr^T
  //   comb_skl  rows 0..63 = c2_so_Wl^T, rows 64..127 = c2_os_Wr^T
  unsigned short* wt_pocc   = (unsigned short*)alloc(32768 * 2);
  unsigned short* wt_pskill = (unsigned short*)alloc(32768 * 2);
  unsigned short* wt_c1osWl = (unsigned short*)alloc(16384 * 2);
  unsigned short* wt_c1osWr = (unsigned short*)alloc(16384 * 2);
  unsigned short* wt_c1soWl = (unsigned short*)alloc(16384 * 2);
  unsigned short* wt_c1soWr = (unsigned short*)alloc(16384 * 2);
  unsigned short* comb_occ  = (unsigned short*)alloc(16384 * 2);
  unsigned short* comb_skl  = (unsigned short*)alloc(16384 * 2);

  // zero-initialized region: bucket counts/cursors + zero bias
  size_t zero_bytes = (size_t)(2 * (NB_S + NB_O)) * 4 + 256;
  char* zero_base = alloc(zero_bytes);
  int* bkcnt_s = (int*)zero_base;
  int* bkcnt_o = bkcnt_s + NB_S;
  int* bcur_s  = bkcnt_o + NB_O;
  int* bcur_o  = bcur_s + NB_S;
  unsigned short* zbias = (unsigned short*)(bcur_o + NB_O);

  int* boff_s = (int*)alloc((NB_S + 1) * 4);
  int* boff_o = (int*)alloc((NB_O + 1) * 4);
  int* off_s = (int*)alloc((N_SKILL + 1) * 4);
  int* off_o = (int*)alloc((N_OCC + 1) * 4);
  int* csr_s = (int*)alloc((size_t)N_EDGE * 4);
  int* csr_o = (int*)alloc((size_t)N_EDGE * 4);
  unsigned* pair_s = (unsigned*)alloc((size_t)N_EDGE * 4);
  unsigned* pair_o = (unsigned*)alloc((size_t)N_EDGE * 4);

  unsigned short* h_occ   = (unsigned short*)alloc((size_t)N_OCC * HID * 2);
  unsigned short* h_skill = (unsigned short*)alloc((size_t)N_SKILL * HID * 2);
  unsigned short* mean_s  = (unsigned short*)alloc((size_t)N_SKILL * HID * 2);
  unsigned short* mean_o  = (unsigned short*)alloc((size_t)N_OCC * HID * 2);
  unsigned short* s1      = (unsigned short*)alloc((size_t)N_SKILL * HID * 2);
  unsigned short* o1      = (unsigned short*)alloc((size_t)N_OCC * HID * 2);
  unsigned short* P_occ   = (unsigned short*)alloc((size_t)N_OCC * HID * 2);
  unsigned short* P_skl   = (unsigned short*)alloc((size_t)N_SKILL * HID * 2);

  const int G_OCC  = (N_OCC + 127) / 128;
  const int G_SKL  = (N_SKILL + 127) / 128;
  const int SM_SKL = (N_SKILL + 3) / 4;
  const int SM_OCC = (N_OCC + 3) / 4;

  hipMemsetAsync(zero_base, 0, zero_bytes, stream);

  k_detect<<<1, 64, 0, stream>>>((const unsigned short*)raw[0], wire_flag);
  k_convert<<<conv_blocks, 256, 0, stream>>>(ct, wire_flag);

  k_transpose_all<<<640, 256, 0, stream>>>(
      c_pWo, wt_pocc, c_pWs, wt_pskill,
      c1osWl, wt_c1osWl, c1osWr, wt_c1osWr,
      c1soWl, wt_c1soWl, c1soWr, wt_c1soWr,
      c2osWl, comb_occ,              // -> comb_occ rows 0..63
      c2osWr, comb_skl + 64 * 128,   // -> comb_skl rows 64..127
      c2soWl, comb_skl,              // -> comb_skl rows 0..63
      c2soWr, comb_occ + 64 * 128);  // -> comb_occ rows 64..127

  // CSR build
  k_bincount<<<2 * BIN_BLKS, 256, 0, stream>>>(edge_occ, edge_skill, bkcnt_s, bkcnt_o);
  k_bscan<<<1, 128, 0, stream>>>(bkcnt_s, bkcnt_o, boff_s, boff_o, off_s, off_o);
  k_bin<<<2 * BIN_BLKS, 256, 0, stream>>>(edge_occ, edge_skill, boff_s, boff_o,
                                          bcur_s, bcur_o, pair_s, pair_o);
  k_build<<<NB_S + NB_O, 256, 0, stream>>>(pair_s, pair_o, boff_s, boff_o,
                                           off_s, off_o, csr_s, csr_o);

  // input projections + relu (read wire x directly; convert in registers)
  k_gemm<128><<<G_OCC, 256, 0, stream>>>((const unsigned short*)raw[0], wt_pocc, D_IN,
                                         nullptr, nullptr, 0,
                                         c_pbo, h_occ, 0, N_OCC, 1, 0, wire_flag, 1);
  k_gemm<128><<<G_SKL, 256, 0, stream>>>((const unsigned short*)raw[1], wt_pskill, D_IN,
                                         nullptr, nullptr, 0,
                                         c_pbs, h_skill, 0, N_SKILL, 1, 0, wire_flag, 1);

  // conv1 aggregation
  k_seg_mean<<<SM_SKL, 256, 0, stream>>>(h_occ, off_s, csr_s, mean_s, N_SKILL);
  k_seg_mean<<<SM_OCC, 256, 0, stream>>>(h_skill, off_o, csr_o, mean_o, N_OCC);

  // conv1 linear
  k_gemm<128><<<G_SKL, 256, 0, stream>>>(mean_s, wt_c1osWl, HID, h_skill, wt_c1osWr, HID,
                                         c1osbl, s1, 0, N_SKILL, 1, 0, wire_flag, 0);
  k_gemm<128><<<G_OCC, 256, 0, stream>>>(mean_o, wt_c1soWl, HID, h_occ, wt_c1soWr, HID,
                                         c1sobl, o1, 0, N_OCC, 1, 0, wire_flag, 0);

  // conv2: project BEFORE aggregating (mean and linear commute):
  //   P_occ = o1 @ [c2_os_Wl | c2_so_Wr],  P_skl = s1 @ [c2_so_Wl | c2_os_Wr]
  k_gemm<128><<<G_OCC, 256, 0, stream>>>(o1, comb_occ, HID, nullptr, nullptr, 0,
                                         zbias, P_occ, 0, N_OCC, 0, 0, wire_flag, 0);
  k_gemm<128><<<G_SKL, 256, 0, stream>>>(s1, comb_skl, HID, nullptr, nullptr, 0,
                                         zbias, P_skl, 0, N_SKILL, 0, 0, wire_flag, 0);

  // conv2 fused aggregate + self + bias -> wire output
  // s2 (skill rows, at element offset N_OCC*64), o2 (occ rows, at offset 0)
  k_seg_out<<<SM_SKL, 256, 0, stream>>>(P_occ, P_skl, off_s, csr_s, c2osbl,
                                        d_out, (size_t)N_OCC * OUT_F, N_SKILL, wire_flag);
  k_seg_out<<<SM_OCC, 256, 0, stream>>>(P_skl, P_occ, off_o, csr_o, c2sobl,
                                        d_out, 0, N_OCC, wire_flag);
}

// Round 4
// 388.009 us; speedup vs baseline: 1.4864x; 1.0515x over previous
//
#include <hip/hip_runtime.h>

#define N_OCC   20000
#define N_SKILL 50000
#define N_EDGE  600000
#define D_IN    256
#define HID     128
#define OUT_F   64

typedef short bf16x8 __attribute__((ext_vector_type(8)));
typedef float f32x4  __attribute__((ext_vector_type(4)));

__device__ __forceinline__ float bf2f(unsigned short u){
  return __uint_as_float(((unsigned)u) << 16);
}
__device__ __forceinline__ unsigned f2bf_bits(float f){
  unsigned i = __float_as_uint(f);
  return (i + 0x7fffu + ((i >> 16) & 1u)) >> 16;   // RNE
}
__device__ __forceinline__ unsigned f2bf_bits_u(unsigned i){
  return (i + 0x7fffu + ((i >> 16) & 1u)) >> 16;   // RNE from raw f32 bits
}
__device__ __forceinline__ unsigned short f2bf(float f){ return (unsigned short)f2bf_bits(f); }

// ---------- wire-dtype detection ----------
__global__ void k_detect(const unsigned short* __restrict__ x, int* __restrict__ flag){
  int lane = threadIdx.x & 63;
  int cnt = 0;
  for (int i = lane; i < 1024; i += 64){
    unsigned e = ((unsigned)x[i] >> 7) & 0xFFu;
    if (e >= 0xE0u) cnt++;
  }
  #pragma unroll
  for (int s = 1; s < 64; s <<= 1) cnt += __shfl_xor(cnt, s, 64);
  if (lane == 0) *flag = (cnt >= 8) ? 1 : 0;   // 1 => wire is f32
}

// ---------- canonicalize WEIGHT tensors to bf16 (x handled in-GEMM) ----------
#define NT_CONV 16
struct ConvTable {
  const void*     src[NT_CONV];
  unsigned short* dst[NT_CONV];
  int             n[NT_CONV];
  int             blk_off[NT_CONV + 1];   // cumulative blocks (2048 elems/block)
};

__global__ void k_convert(ConvTable t, const int* __restrict__ flag){
  int isf32 = *flag;
  int b = blockIdx.x;
  int ti = 0;
  while (ti < NT_CONV - 1 && b >= t.blk_off[ti + 1]) ti++;
  int lb = b - t.blk_off[ti];
  int i = (lb * 256 + (int)threadIdx.x) * 8;     // element index (8 per thread)
  if (i >= t.n[ti]) return;
  unsigned short* dst = t.dst[ti];
  if (isf32){
    const float* s = (const float*)t.src[ti];
    uint4 lo = *(const uint4*)(s + i);
    uint4 hi = *(const uint4*)(s + i + 4);
    uint4 o;
    o.x = f2bf_bits_u(lo.x) | (f2bf_bits_u(lo.y) << 16);
    o.y = f2bf_bits_u(lo.z) | (f2bf_bits_u(lo.w) << 16);
    o.z = f2bf_bits_u(hi.x) | (f2bf_bits_u(hi.y) << 16);
    o.w = f2bf_bits_u(hi.z) | (f2bf_bits_u(hi.w) << 16);
    *(uint4*)(dst + i) = o;
  } else {
    *(uint4*)(dst + i) = *(const uint4*)((const unsigned short*)t.src[ti] + i);
  }
}

// ---------- transpose weight matrices W[K][N] -> WT[N][K] ----------
__global__ void k_transpose_all(
    const unsigned short* pWo, unsigned short* tWo,   // 256x128
    const unsigned short* pWs, unsigned short* tWs,   // 256x128
    const unsigned short* w2,  unsigned short* t2,    // 128x128
    const unsigned short* w3,  unsigned short* t3,
    const unsigned short* w4,  unsigned short* t4,
    const unsigned short* w5,  unsigned short* t5,
    const unsigned short* w6,  unsigned short* t6,    // 128x64
    const unsigned short* w7,  unsigned short* t7,
    const unsigned short* w8,  unsigned short* t8,
    const unsigned short* w9,  unsigned short* t9)
{
  int idx = blockIdx.x * blockDim.x + threadIdx.x;
  const unsigned short* in; unsigned short* out; int K, N, base;
  if      (idx <  32768){ in=pWo; out=tWo; K=256; N=128; base=0; }
  else if (idx <  65536){ in=pWs; out=tWs; K=256; N=128; base=32768; }
  else if (idx <  81920){ in=w2;  out=t2;  K=128; N=128; base=65536; }
  else if (idx <  98304){ in=w3;  out=t3;  K=128; N=128; base=81920; }
  else if (idx < 114688){ in=w4;  out=t4;  K=128; N=128; base=98304; }
  else if (idx < 131072){ in=w5;  out=t5;  K=128; N=128; base=114688; }
  else if (idx < 139264){ in=w6;  out=t6;  K=128; N=64;  base=131072; }
  else if (idx < 147456){ in=w7;  out=t7;  K=128; N=64;  base=139264; }
  else if (idx < 155648){ in=w8;  out=t8;  K=128; N=64;  base=147456; }
  else if (idx < 163840){ in=w9;  out=t9;  K=128; N=64;  base=155648; }
  else return;
  int li = idx - base;
  int k = li / N, n = li - k * N;
  out[n * K + k] = in[li];
}

// ---------- CSR build: bucket counting sort, no node-level global atomics ----------
#define EPB      4096
#define BIN_BLKS ((N_EDGE + EPB - 1) / EPB)         // 147
#define SH_S 9
#define SH_O 8
#define NB_S ((N_SKILL + (1 << SH_S) - 1) >> SH_S)  // 98
#define NB_O ((N_OCC   + (1 << SH_O) - 1) >> SH_O)  // 79

__launch_bounds__(256)
__global__ void k_bincount(const int* __restrict__ eo, const int* __restrict__ es,
                           int* __restrict__ bkcnt_s, int* __restrict__ bkcnt_o)
{
  int b = blockIdx.x;
  int side = (b >= BIN_BLKS) ? 1 : 0;
  int lb = side ? b - BIN_BLKS : b;
  const int* dste = side ? eo : es;
  int* bkcnt = side ? bkcnt_o : bkcnt_s;
  const int NB = side ? NB_O : NB_S;
  const int SH = side ? SH_O : SH_S;
  __shared__ int cntL[NB_S];
  for (int i = threadIdx.x; i < NB; i += 256) cntL[i] = 0;
  __syncthreads();
  int e0 = lb * EPB, e1 = min(e0 + EPB, N_EDGE);
  for (int e = e0 + threadIdx.x; e < e1; e += 256)
    atomicAdd(&cntL[dste[e] >> SH], 1);
  __syncthreads();
  for (int i = threadIdx.x; i < NB; i += 256)
    if (cntL[i]) atomicAdd(&bkcnt[i], cntL[i]);
}

__global__ void k_bscan(const int* __restrict__ bkcnt_s, const int* __restrict__ bkcnt_o,
                        int* __restrict__ boff_s, int* __restrict__ boff_o,
                        int* __restrict__ off_s, int* __restrict__ off_o)
{
  __shared__ int sc[128];
  int t = threadIdx.x;   // 128 threads
  int v = (t < NB_S) ? bkcnt_s[t] : 0;
  sc[t] = v;
  __syncthreads();
  for (int d = 1; d < 128; d <<= 1){
    int u = (t >= d) ? sc[t - d] : 0;
    __syncthreads();
    sc[t] += u;
    __syncthreads();
  }
  if (t < NB_S) boff_s[t] = sc[t] - v;
  if (t == 0){ boff_s[NB_S] = N_EDGE; off_s[N_SKILL] = N_EDGE; }
  __syncthreads();
  int v2 = (t < NB_O) ? bkcnt_o[t] : 0;
  sc[t] = v2;
  __syncthreads();
  for (int d = 1; d < 128; d <<= 1){
    int u = (t >= d) ? sc[t - d] : 0;
    __syncthreads();
    sc[t] += u;
    __syncthreads();
  }
  if (t < NB_O) boff_o[t] = sc[t] - v2;
  if (t == 0){ boff_o[NB_O] = N_EDGE; off_o[N_OCC] = N_EDGE; }
}

// packed pair: (local_dst << 16) | src   (src < 65536, local_dst < 512)
__launch_bounds__(256)
__global__ void k_bin(const int* __restrict__ eo, const int* __restrict__ es,
                      const int* __restrict__ boff_s, const int* __restrict__ boff_o,
                      int* __restrict__ bcur_s, int* __restrict__ bcur_o,
                      unsigned* __restrict__ pair_s, unsigned* __restrict__ pair_o)
{
  int b = blockIdx.x;
  int side = (b >= BIN_BLKS) ? 1 : 0;
  int lb = side ? b - BIN_BLKS : b;
  const int* dste = side ? eo : es;
  const int* srce = side ? es : eo;
  const int* boff = side ? boff_o : boff_s;
  int* bcur       = side ? bcur_o : bcur_s;
  unsigned* pairs = side ? pair_o : pair_s;
  const int NB = side ? NB_O : NB_S;
  const int SH = side ? SH_O : SH_S;

  __shared__ int cntL[NB_S], gbaseL[NB_S], lbaseL[NB_S], runL[NB_S];
  __shared__ int sc[128];
  __shared__ unsigned stage[EPB];   // 16 KB
  __shared__ int gpos[EPB];         // 16 KB

  int e0 = lb * EPB;
  int e1 = min(e0 + EPB, N_EDGE);

  for (int i = threadIdx.x; i < NB; i += 256){ cntL[i] = 0; runL[i] = 0; }
  __syncthreads();
  for (int e = e0 + threadIdx.x; e < e1; e += 256)
    atomicAdd(&cntL[dste[e] >> SH], 1);
  __syncthreads();
  if (threadIdx.x < 128) sc[threadIdx.x] = (threadIdx.x < NB) ? cntL[threadIdx.x] : 0;
  __syncthreads();
  for (int d = 1; d < 128; d <<= 1){
    int v = 0;
    if (threadIdx.x < 128 && threadIdx.x >= d) v = sc[threadIdx.x - d];
    __syncthreads();
    if (threadIdx.x < 128) sc[threadIdx.x] += v;
    __syncthreads();
  }
  if (threadIdx.x < NB){
    int c = cntL[threadIdx.x];
    lbaseL[threadIdx.x] = sc[threadIdx.x] - c;
    gbaseL[threadIdx.x] = boff[threadIdx.x] + atomicAdd(&bcur[threadIdx.x], c);
  }
  __syncthreads();
  for (int e = e0 + threadIdx.x; e < e1; e += 256){
    int d = dste[e], s = srce[e];
    int bk = d >> SH;
    int r = atomicAdd(&runL[bk], 1);
    int lp = lbaseL[bk] + r;
    stage[lp] = ((unsigned)(d & ((1 << SH) - 1)) << 16) | (unsigned)s;
    gpos[lp] = gbaseL[bk] + r;
  }
  __syncthreads();
  int tot = e1 - e0;
  for (int i = threadIdx.x; i < tot; i += 256)
    pairs[gpos[i]] = stage[i];     // consecutive within each bucket run -> coalesced
}

__launch_bounds__(256)
__global__ void k_build(const unsigned* __restrict__ pair_s, const unsigned* __restrict__ pair_o,
                        const int* __restrict__ boff_s, const int* __restrict__ boff_o,
                        int* __restrict__ off_s, int* __restrict__ off_o,
                        int* __restrict__ csr_s, int* __restrict__ csr_o)
{
  int b = blockIdx.x;
  int side = (b >= NB_S) ? 1 : 0;
  int lb = side ? b - NB_S : b;
  const unsigned* pairs = side ? pair_o : pair_s;
  const int* boff = side ? boff_o : boff_s;
  int* off = side ? off_o : off_s;
  int* csr = side ? csr_o : csr_s;
  int SH = side ? SH_O : SH_S;
  int nd_tot = side ? N_OCC : N_SKILL;
  int d0 = lb << SH;
  int d1 = min(d0 + (1 << SH), nd_tot);
  int nd = d1 - d0;
  int p0 = boff[lb], p1 = boff[lb + 1];

  __shared__ int cntL[1 << SH_S];
  __shared__ int offL[1 << SH_S];
  __shared__ int ws[4];
  int t = threadIdx.x;
  cntL[t] = 0; cntL[t + 256] = 0;
  __syncthreads();
  for (int i = p0 + t; i < p1; i += 256)
    atomicAdd(&cntL[pairs[i] >> 16], 1);
  __syncthreads();
  int a0 = cntL[2 * t], a1 = cntL[2 * t + 1];
  int s = a0 + a1;
  int lane = t & 63, wv = t >> 6;
  int x = s;
  #pragma unroll
  for (int d = 1; d < 64; d <<= 1){ int u = __shfl_up(x, d, 64); if (lane >= d) x += u; }
  if (lane == 63) ws[wv] = x;
  __syncthreads();
  int woff = 0;
  for (int w = 0; w < wv; ++w) woff += ws[w];
  int excl = woff + x - s;
  offL[2 * t] = excl;
  offL[2 * t + 1] = excl + a0;
  __syncthreads();
  for (int i = t; i < nd; i += 256) off[d0 + i] = p0 + offL[i];
  cntL[t] = 0; cntL[t + 256] = 0;
  __syncthreads();
  for (int i = p0 + t; i < p1; i += 256){
    unsigned pr = pairs[i];
    int d = (int)(pr >> 16);
    int p = p0 + offL[d] + atomicAdd(&cntL[d], 1);
    csr[p] = (int)(pr & 0xFFFFu);   // scattered only within one L2-resident window
  }
}

// ---------- fused-pair segment mean: one wave per dst node, 128 bf16 feats ----------
__launch_bounds__(256)
__global__ void k_seg_mean2(const unsigned short* __restrict__ feat0,
                            const int* __restrict__ off0, const int* __restrict__ csr0,
                            unsigned short* __restrict__ out0, int n0, int nb0,
                            const unsigned short* __restrict__ feat1,
                            const int* __restrict__ off1, const int* __restrict__ csr1,
                            unsigned short* __restrict__ out1, int n1)
{
  int b = blockIdx.x;
  int side = (b >= nb0) ? 1 : 0;
  const unsigned short* feat = side ? feat1 : feat0;
  const int* off = side ? off1 : off0;
  const int* csr = side ? csr1 : csr0;
  unsigned short* out = side ? out1 : out0;
  int n_dst = side ? n1 : n0;
  int gw = (side ? b - nb0 : b) * 4 + (int)(threadIdx.x >> 6);
  if (gw >= n_dst) return;
  int lane = threadIdx.x & 63;
  int r = lane >> 4;
  int c = lane & 15;
  int beg = off[gw], end = off[gw + 1];
  float acc[8];
  #pragma unroll
  for (int j = 0; j < 8; ++j) acc[j] = 0.0f;
  for (int e = beg + r; e < end; e += 4){
    int s = csr[e];
    uint4 v = *(const uint4*)(feat + ((size_t)s << 7) + (c << 3));
    acc[0] += __uint_as_float(v.x << 16); acc[1] += __uint_as_float(v.x & 0xffff0000u);
    acc[2] += __uint_as_float(v.y << 16); acc[3] += __uint_as_float(v.y & 0xffff0000u);
    acc[4] += __uint_as_float(v.z << 16); acc[5] += __uint_as_float(v.z & 0xffff0000u);
    acc[6] += __uint_as_float(v.w << 16); acc[7] += __uint_as_float(v.w & 0xffff0000u);
  }
  #pragma unroll
  for (int j = 0; j < 8; ++j){
    acc[j] += __shfl_xor(acc[j], 16, 64);
    acc[j] += __shfl_xor(acc[j], 32, 64);
  }
  if (r == 0){
    int cnt = end - beg;
    float inv = 1.0f / (float)(cnt > 0 ? cnt : 1);
    uint4 o;
    o.x = f2bf_bits(acc[0] * inv) | (f2bf_bits(acc[1] * inv) << 16);
    o.y = f2bf_bits(acc[2] * inv) | (f2bf_bits(acc[3] * inv) << 16);
    o.z = f2bf_bits(acc[4] * inv) | (f2bf_bits(acc[5] * inv) << 16);
    o.w = f2bf_bits(acc[6] * inv) | (f2bf_bits(acc[7] * inv) << 16);
    *(uint4*)(out + ((size_t)gw << 7) + (c << 3)) = o;
  }
}

// ---------- fused-pair conv2 output: mean_gather(Pg[:,0:64]) + Ps[d,64:128] + bias ----------
__launch_bounds__(256)
__global__ void k_seg_out2(const unsigned short* __restrict__ Pg0, const unsigned short* __restrict__ Ps0,
                           const int* __restrict__ off0, const int* __restrict__ csr0,
                           const unsigned short* __restrict__ bias0, size_t o_off0, int n0, int nb0,
                           const unsigned short* __restrict__ Pg1, const unsigned short* __restrict__ Ps1,
                           const int* __restrict__ off1, const int* __restrict__ csr1,
                           const unsigned short* __restrict__ bias1, size_t o_off1, int n1,
                           void* __restrict__ out, const int* __restrict__ wire_flag)
{
  int b = blockIdx.x;
  int side = (b >= nb0) ? 1 : 0;
  const unsigned short* Pg = side ? Pg1 : Pg0;
  const unsigned short* Ps = side ? Ps1 : Ps0;
  const int* off = side ? off1 : off0;
  const int* csr = side ? csr1 : csr0;
  const unsigned short* bias = side ? bias1 : bias0;
  size_t o_off = side ? o_off1 : o_off0;
  int n_dst = side ? n1 : n0;
  int gw = (side ? b - nb0 : b) * 4 + (int)(threadIdx.x >> 6);
  if (gw >= n_dst) return;
  int lane = threadIdx.x & 63;
  int r = lane >> 3;          // 8 edge groups
  int c = lane & 7;           // 8 chunks of 8 bf16 = 64 feats
  int beg = off[gw], end = off[gw + 1];
  float acc[8];
  #pragma unroll
  for (int j = 0; j < 8; ++j) acc[j] = 0.0f;
  for (int e = beg + r; e < end; e += 8){
    int s = csr[e];
    uint4 v = *(const uint4*)(Pg + ((size_t)s << 7) + (c << 3));
    acc[0] += __uint_as_float(v.x << 16); acc[1] += __uint_as_float(v.x & 0xffff0000u);
    acc[2] += __uint_as_float(v.y << 16); acc[3] += __uint_as_float(v.y & 0xffff0000u);
    acc[4] += __uint_as_float(v.z << 16); acc[5] += __uint_as_float(v.z & 0xffff0000u);
    acc[6] += __uint_as_float(v.w << 16); acc[7] += __uint_as_float(v.w & 0xffff0000u);
  }
  #pragma unroll
  for (int j = 0; j < 8; ++j){
    acc[j] += __shfl_xor(acc[j], 8, 64);
    acc[j] += __shfl_xor(acc[j], 16, 64);
    acc[j] += __shfl_xor(acc[j], 32, 64);
  }
  if (r == 0){
    int cnt = end - beg;
    float inv = 1.0f / (float)(cnt > 0 ? cnt : 1);
    uint4 sv = *(const uint4*)(Ps + ((size_t)gw << 7) + 64 + (c << 3));
    uint4 bv = *(const uint4*)(bias + (c << 3));
    float o0 = acc[0] * inv + __uint_as_float(sv.x << 16)         + __uint_as_float(bv.x << 16);
    float o1 = acc[1] * inv + __uint_as_float(sv.x & 0xffff0000u) + __uint_as_float(bv.x & 0xffff0000u);
    float o2 = acc[2] * inv + __uint_as_float(sv.y << 16)         + __uint_as_float(bv.y << 16);
    float o3 = acc[3] * inv + __uint_as_float(sv.y & 0xffff0000u) + __uint_as_float(bv.y & 0xffff0000u);
    float o4 = acc[4] * inv + __uint_as_float(sv.z << 16)         + __uint_as_float(bv.z << 16);
    float o5 = acc[5] * inv + __uint_as_float(sv.z & 0xffff0000u) + __uint_as_float(bv.z & 0xffff0000u);
    float o6 = acc[6] * inv + __uint_as_float(sv.w << 16)         + __uint_as_float(bv.w << 16);
    float o7 = acc[7] * inv + __uint_as_float(sv.w & 0xffff0000u) + __uint_as_float(bv.w & 0xffff0000u);
    size_t eoff = o_off + (size_t)gw * 64 + (c << 3);
    if (*wire_flag){
      float* op = (float*)out + eoff;
      uint4 w0, w1;
      w0.x = __float_as_uint(o0); w0.y = __float_as_uint(o1);
      w0.z = __float_as_uint(o2); w0.w = __float_as_uint(o3);
      w1.x = __float_as_uint(o4); w1.y = __float_as_uint(o5);
      w1.z = __float_as_uint(o6); w1.w = __float_as_uint(o7);
      *(uint4*)op = w0;
      *(uint4*)(op + 4) = w1;
    } else {
      unsigned short* op = (unsigned short*)out + eoff;
      uint4 w;
      w.x = f2bf_bits(o0) | (f2bf_bits(o1) << 16);
      w.y = f2bf_bits(o2) | (f2bf_bits(o3) << 16);
      w.z = f2bf_bits(o4) | (f2bf_bits(o5) << 16);
      w.w = f2bf_bits(o6) | (f2bf_bits(o7) << 16);
      *(uint4*)op = w;
    }
  }
}

// ---------- fused-pair GEMM: C = act(A1@W1 [+ A2@W2] + bias), N=128, bf16 out ----------
// 64 rows/block (1 wave = 16 rows x 128 cols). Both problem "sides" in one grid.
// K1/K2 compile-time for unrolling; AW: A1 is wire (f32 if *wire_flag).
template<int K1, int HASA2, int AW>
__launch_bounds__(256)
__global__ void k_gemm2(const unsigned short* __restrict__ A1_0, const unsigned short* __restrict__ A1_1,
                        const unsigned short* __restrict__ W1T_0, const unsigned short* __restrict__ W1T_1,
                        const unsigned short* __restrict__ A2_0, const unsigned short* __restrict__ A2_1,
                        const unsigned short* __restrict__ W2T_0, const unsigned short* __restrict__ W2T_1,
                        const unsigned short* __restrict__ bias_0, const unsigned short* __restrict__ bias_1,
                        unsigned short* __restrict__ C_0, unsigned short* __restrict__ C_1,
                        int M0, int M1, int nb0, int do_relu,
                        const int* __restrict__ wire_flag)
{
  int b = blockIdx.x;
  int side = (b >= nb0) ? 1 : 0;
  const unsigned short* A1  = side ? A1_1  : A1_0;
  const unsigned short* W1T = side ? W1T_1 : W1T_0;
  const unsigned short* A2  = side ? A2_1  : A2_0;
  const unsigned short* W2T = side ? W2T_1 : W2T_0;
  const unsigned short* bias= side ? bias_1: bias_0;
  unsigned short* C = side ? C_1 : C_0;
  int M = side ? M1 : M0;
  int lb = side ? b - nb0 : b;

  const int lane = threadIdx.x & 63;
  const int wv   = threadIdx.x >> 6;
  const int q    = lane >> 4;
  const int mr   = lane & 15;
  const int m0   = lb * 64 + wv * 16;
  const int koff = q * 8;
  const int row  = m0 + mr;
  const bool rok = (row < M);
  const int awf  = AW ? *wire_flag : 0;

  f32x4 acc[8];
  #pragma unroll
  for (int nt = 0; nt < 8; ++nt)
    #pragma unroll
    for (int j = 0; j < 4; ++j) acc[nt][j] = 0.0f;

  #pragma unroll 2
  for (int k0 = 0; k0 < K1; k0 += 32){
    bf16x8 a1, b1[8];
    if (rok){
      if (AW && awf){
        const float* ar = (const float*)A1 + (size_t)row * K1 + k0 + koff;
        uint4 lo = *(const uint4*)ar;
        uint4 hi = *(const uint4*)(ar + 4);
        union { bf16x8 v; uint4 u; } cv;
        cv.u.x = f2bf_bits_u(lo.x) | (f2bf_bits_u(lo.y) << 16);
        cv.u.y = f2bf_bits_u(lo.z) | (f2bf_bits_u(lo.w) << 16);
        cv.u.z = f2bf_bits_u(hi.x) | (f2bf_bits_u(hi.y) << 16);
        cv.u.w = f2bf_bits_u(hi.z) | (f2bf_bits_u(hi.w) << 16);
        a1 = cv.v;
      } else {
        a1 = *(const bf16x8*)(A1 + (size_t)row * K1 + k0 + koff);
      }
    } else {
      #pragma unroll
      for (int j = 0; j < 8; ++j) a1[j] = 0;
    }
    #pragma unroll
    for (int nt = 0; nt < 8; ++nt)
      b1[nt] = *(const bf16x8*)(W1T + (size_t)(nt * 16 + mr) * K1 + k0 + koff);

    bf16x8 a2, b2[8];
    if (HASA2){
      if (rok){
        a2 = *(const bf16x8*)(A2 + (size_t)row * K1 + k0 + koff);
      } else {
        #pragma unroll
        for (int j = 0; j < 8; ++j) a2[j] = 0;
      }
      #pragma unroll
      for (int nt = 0; nt < 8; ++nt)
        b2[nt] = *(const bf16x8*)(W2T + (size_t)(nt * 16 + mr) * K1 + k0 + koff);
    }

    #pragma unroll
    for (int nt = 0; nt < 8; ++nt)
      acc[nt] = __builtin_amdgcn_mfma_f32_16x16x32_bf16(a1, b1[nt], acc[nt], 0, 0, 0);
    if (HASA2){
      #pragma unroll
      for (int nt = 0; nt < 8; ++nt)
        acc[nt] = __builtin_amdgcn_mfma_f32_16x16x32_bf16(a2, b2[nt], acc[nt], 0, 0, 0);
    }
  }

  #pragma unroll
  for (int nt = 0; nt < 8; ++nt){
    int col = nt * 16 + mr;
    float bv = bf2f(bias[col]);
    #pragma unroll
    for (int r4 = 0; r4 < 4; ++r4){
      int orow = m0 + q * 4 + r4;
      if (orow < M){
        float v = acc[nt][r4] + bv;
        if (do_relu) v = fmaxf(v, 0.0f);
        C[(size_t)orow * 128 + col] = f2bf(v);
      }
    }
  }
}

extern "C" void kernel_launch(void* const* d_in, const int* in_sizes, int n_in,
                              void* d_out, int out_size, void* d_ws, size_t ws_size,
                              hipStream_t stream)
{
  const void* raw[20];
  for (int i = 0; i < 20; ++i) raw[i] = d_in[i];
  const int* edge_occ   = (const int*)d_in[2];
  const int* edge_skill = (const int*)d_in[3];

  char* ws = (char*)d_ws;
  size_t off = 0;
  auto alloc = [&](size_t bytes) -> char* {
    char* p = ws + off;
    off = (off + bytes + 255) & ~(size_t)255;
    return p;
  };

  int* wire_flag = (int*)alloc(4);

  // canonical bf16 copies of the 16 WEIGHT tensors (x stays on the wire)
  static const int cn[NT_CONV] = {
    D_IN * HID, HID, D_IN * HID, HID,            // pW_occ, pb_occ, pW_skill, pb_skill
    HID * HID, HID, HID * HID,                   // c1_os_Wl, bl, Wr
    HID * HID, HID, HID * HID,                   // c1_so_Wl, bl, Wr
    HID * OUT_F, OUT_F, HID * OUT_F,             // c2_os_Wl, bl, Wr
    HID * OUT_F, OUT_F, HID * OUT_F              // c2_so_Wl, bl, Wr
  };
  static const int raw_idx[NT_CONV] = {4,5,6,7, 8,9,10, 11,12,13, 14,15,16, 17,18,19};
  unsigned short* can[NT_CONV];
  for (int i = 0; i < NT_CONV; ++i) can[i] = (unsigned short*)alloc((size_t)cn[i] * 2);

  ConvTable ct;
  ct.blk_off[0] = 0;
  for (int i = 0; i < NT_CONV; ++i){
    ct.src[i] = raw[raw_idx[i]];
    ct.dst[i] = can[i];
    ct.n[i]   = cn[i];
    ct.blk_off[i + 1] = ct.blk_off[i] + (cn[i] + 2047) / 2048;
  }
  const int conv_blocks = ct.blk_off[NT_CONV];

  const unsigned short* c_pWo = can[0],  *c_pbo = can[1];
  const unsigned short* c_pWs = can[2],  *c_pbs = can[3];
  const unsigned short* c1osWl = can[4], *c1osbl = can[5], *c1osWr = can[6];
  const unsigned short* c1soWl = can[7], *c1sobl = can[8], *c1soWr = can[9];
  const unsigned short* c2osWl = can[10], *c2osbl = can[11], *c2osWr = can[12];
  const unsigned short* c2soWl = can[13], *c2sobl = can[14], *c2soWr = can[15];

  // transposed weights; conv2 weights land in combined [Wl | Wr] 128x128 blocks:
  //   comb_occ  rows 0..63 = c2_os_Wl^T, rows 64..127 = c2_so_Wr^T
  //   comb_skl  rows 0..63 = c2_so_Wl^T, rows 64..127 = c2_os_Wr^T
  unsigned short* wt_pocc   = (unsigned short*)alloc(32768 * 2);
  unsigned short* wt_pskill = (unsigned short*)alloc(32768 * 2);
  unsigned short* wt_c1osWl = (unsigned short*)alloc(16384 * 2);
  unsigned short* wt_c1osWr = (unsigned short*)alloc(16384 * 2);
  unsigned short* wt_c1soWl = (unsigned short*)alloc(16384 * 2);
  unsigned short* wt_c1soWr = (unsigned short*)alloc(16384 * 2);
  unsigned short* comb_occ  = (unsigned short*)alloc(16384 * 2);
  unsigned short* comb_skl  = (unsigned short*)alloc(16384 * 2);

  // zero-initialized region: bucket counts/cursors + zero bias
  size_t zero_bytes = (size_t)(2 * (NB_S + NB_O)) * 4 + 256;
  char* zero_base = alloc(zero_bytes);
  int* bkcnt_s = (int*)zero_base;
  int* bkcnt_o = bkcnt_s + NB_S;
  int* bcur_s  = bkcnt_o + NB_O;
  int* bcur_o  = bcur_s + NB_S;
  unsigned short* zbias = (unsigned short*)(bcur_o + NB_O);

  int* boff_s = (int*)alloc((NB_S + 1) * 4);
  int* boff_o = (int*)alloc((NB_O + 1) * 4);
  int* off_s = (int*)alloc((N_SKILL + 1) * 4);
  int* off_o = (int*)alloc((N_OCC + 1) * 4);
  int* csr_s = (int*)alloc((size_t)N_EDGE * 4);
  int* csr_o = (int*)alloc((size_t)N_EDGE * 4);
  unsigned* pair_s = (unsigned*)alloc((size_t)N_EDGE * 4);
  unsigned* pair_o = (unsigned*)alloc((size_t)N_EDGE * 4);

  unsigned short* h_occ   = (unsigned short*)alloc((size_t)N_OCC * HID * 2);
  unsigned short* h_skill = (unsigned short*)alloc((size_t)N_SKILL * HID * 2);
  unsigned short* mean_s  = (unsigned short*)alloc((size_t)N_SKILL * HID * 2);
  unsigned short* mean_o  = (unsigned short*)alloc((size_t)N_OCC * HID * 2);
  unsigned short* s1      = (unsigned short*)alloc((size_t)N_SKILL * HID * 2);
  unsigned short* o1      = (unsigned short*)alloc((size_t)N_OCC * HID * 2);
  unsigned short* P_occ   = (unsigned short*)alloc((size_t)N_OCC * HID * 2);
  unsigned short* P_skl   = (unsigned short*)alloc((size_t)N_SKILL * HID * 2);

  const int GB_OCC = (N_OCC + 63) / 64;     // 313
  const int GB_SKL = (N_SKILL + 63) / 64;   // 782
  const int SM_SKL = (N_SKILL + 3) / 4;
  const int SM_OCC = (N_OCC + 3) / 4;

  hipMemsetAsync(zero_base, 0, zero_bytes, stream);

  k_detect<<<1, 64, 0, stream>>>((const unsigned short*)raw[0], wire_flag);
  k_convert<<<conv_blocks, 256, 0, stream>>>(ct, wire_flag);

  k_transpose_all<<<640, 256, 0, stream>>>(
      c_pWo, wt_pocc, c_pWs, wt_pskill,
      c1osWl, wt_c1osWl, c1osWr, wt_c1osWr,
      c1soWl, wt_c1soWl, c1soWr, wt_c1soWr,
      c2osWl, comb_occ,              // -> comb_occ rows 0..63
      c2osWr, comb_skl + 64 * 128,   // -> comb_skl rows 64..127
      c2soWl, comb_skl,              // -> comb_skl rows 0..63
      c2soWr, comb_occ + 64 * 128);  // -> comb_occ rows 64..127

  // CSR build
  k_bincount<<<2 * BIN_BLKS, 256, 0, stream>>>(edge_occ, edge_skill, bkcnt_s, bkcnt_o);
  k_bscan<<<1, 128, 0, stream>>>(bkcnt_s, bkcnt_o, boff_s, boff_o, off_s, off_o);
  k_bin<<<2 * BIN_BLKS, 256, 0, stream>>>(edge_occ, edge_skill, boff_s, boff_o,
                                          bcur_s, bcur_o, pair_s, pair_o);
  k_build<<<NB_S + NB_O, 256, 0, stream>>>(pair_s, pair_o, boff_s, boff_o,
                                           off_s, off_o, csr_s, csr_o);

  // input projections + relu (both node types, one launch; wire x converted in-register)
  k_gemm2<256, 0, 1><<<GB_OCC + GB_SKL, 256, 0, stream>>>(
      (const unsigned short*)raw[0], (const unsigned short*)raw[1],
      wt_pocc, wt_pskill, nullptr, nullptr, nullptr, nullptr,
      c_pbo, c_pbs, h_occ, h_skill, N_OCC, N_SKILL, GB_OCC, 1, wire_flag);

  // conv1 aggregation (both sides, one launch)
  k_seg_mean2<<<SM_SKL + SM_OCC, 256, 0, stream>>>(
      h_occ, off_s, csr_s, mean_s, N_SKILL, SM_SKL,
      h_skill, off_o, csr_o, mean_o, N_OCC);

  // conv1 linear (both sides, one launch)
  k_gemm2<128, 1, 0><<<GB_SKL + GB_OCC, 256, 0, stream>>>(
      mean_s, mean_o, wt_c1osWl, wt_c1soWl,
      h_skill, h_occ, wt_c1osWr, wt_c1soWr,
      c1osbl, c1sobl, s1, o1, N_SKILL, N_OCC, GB_SKL, 1, wire_flag);

  // conv2: project BEFORE aggregating (mean and linear commute):
  //   P_occ = o1 @ [c2_os_Wl | c2_so_Wr],  P_skl = s1 @ [c2_so_Wl | c2_os_Wr]
  k_gemm2<128, 0, 0><<<GB_OCC + GB_SKL, 256, 0, stream>>>(
      o1, s1, comb_occ, comb_skl, nullptr, nullptr, nullptr, nullptr,
      zbias, zbias, P_occ, P_skl, N_OCC, N_SKILL, GB_OCC, 0, wire_flag);

  // conv2 fused aggregate + self + bias -> wire output (both sides, one launch)
  // s2 (skill rows) at element offset N_OCC*64, o2 (occ rows) at offset 0
  k_seg_out2<<<SM_SKL + SM_OCC, 256, 0, stream>>>(
      P_occ, P_skl, off_s, csr_s, c2osbl, (size_t)N_OCC * OUT_F, N_SKILL, SM_SKL,
      P_skl, P_occ, off_o, csr_o, c2sobl, 0, N_OCC,
      d_out, wire_flag);
}